// Round 4
// baseline (612.816 us; speedup 1.0000x reference)
//
#include <hip/hip_runtime.h>
#include <hip/hip_bf16.h>

#define N_NODES 10000
#define N_EDGES 160000
#define DIM     128
#define NBASIS  16
#define LDT     136   // LDS row stride (bf16); 272B row, 16B aligned
#define NFE     (N_NODES*DIM)   // 1,280,000 elements per plane

typedef __bf16 bf16x8 __attribute__((ext_vector_type(8)));
typedef __bf16 bf16x4 __attribute__((ext_vector_type(4)));
typedef __bf16 bf16x2 __attribute__((ext_vector_type(2)));
typedef float  f32x4  __attribute__((ext_vector_type(4)));

__device__ __forceinline__ float silu_f(float x){
  return x * (1.0f / (1.0f + __expf(-x)));
}
__device__ __forceinline__ f32x4 mfma16(bf16x8 a, bf16x8 b, f32x4 c){
  return __builtin_amdgcn_mfma_f32_16x16x32_bf16(a,b,c,0,0,0);
}

// Swizzled weight layout: frag (kc,ni,lane) at Wz[(kc*512+ni*64+lane)*8+j].
// Design log: r9 LDS weights; r10 operand-swap; r11 fused mij+segsum;
// r12 reg radW; r13 node-MLP merge; r16/r17 in-kernel fi/phi reduction;
// r18 ping-pong sW reg-staging (1 barrier/phase) -> 504us (mlp_layer 90us).
// r19 FAILED (694): (256,4) on unified VGPR/AGPR file -> 64V, spills.
// r20 FAILED (641): direct-global weights latency-serialize (no LDS amort).
// r21 FAILED (531): global_load_lds staging -> vmcnt(0) drain at each
// barrier couples waves to slowest DMA; reg-staging overlaps better.
// => r18 staging pipeline is locally optimal. STOP TOUCHING IT.
// r22: attack the OTHER 250us (mij_segsum/node_update/mlp_a, 11 dispatches).
// Layer restructured to 2 kernels: mij production (gathers+radial+segsum
// atomics) moves INTO the edge kernel (mij lives only in LDS -- the 40MB
// tensor + 80MB/layer L3 round-trip dies); R/u node-MLPs move into a fused
// node kernel (R,u MLPs + di/scal/xi update + next layer's a-MLP; Rv/uv
// stay in regs, xi->a-GEMM via LDS). Ordering holds: edge kernel completes
// xi segsum before node kernel reads xi. 14 -> 8 dispatches.
// r8 lesson: smaller edge tiles double chip-wide weight traffic.
// r6 lesson (re-learned r19): never force min-waves below live state.

struct WPtrs { const float* p[11]; };

// ===========================================================================
// Edge kernel: mij (LDS-only) + xi segsum + F/f[/r] MLPs + fi/phi reduction.
// 128 edges/block, 4 waves, wave owns 32 edges (rows wv*32..wv*32+31).
// ===========================================================================
template<bool WITH_R>
__global__ __launch_bounds__(256,2) void mlp_edge(
    const __bf16* __restrict__ ai,
    const int*    __restrict__ esrc, const int* __restrict__ edst,
    const float*  __restrict__ swv,  const float* __restrict__ rbG,
    const float*  __restrict__ radW, const float* __restrict__ radB,
    const float*  __restrict__ dirv,
    const __bf16* __restrict__ fW1z, const float* __restrict__ fb1,
    const __bf16* __restrict__ fW2z, const float* __restrict__ fb2,
    const __bf16* __restrict__ FW1z, const float* __restrict__ Fb1,
    const float*  __restrict__ FW2v, const float* __restrict__ Fb2,
    const __bf16* __restrict__ rW1z, const float* __restrict__ rb1,
    const __bf16* __restrict__ rW2z, const float* __restrict__ rb2,
    float* __restrict__ xiG, float* __restrict__ fiG, float* __restrict__ phiG)
{
  __shared__ __bf16 sH[128*LDT];        // 34816 B (mij -> hidden -> outputs)
  __shared__ __bf16 sW[2][8192];        // 32768 B ping-pong weight staging
  __shared__ float  sRb[128*NBASIS];    //  8192 B
  __shared__ float  sDir[128*4];        //  2048 B
  __shared__ int    sE[128];            //   512 B
  __shared__ int    sD[128];            //   512 B
  __shared__ float  sSw[128];           //   512 B   total 79360 -> 2 blk/CU
  const int tid=threadIdx.x, lane=tid&63, wv=tid>>6, l15=lane&15, quad=lane>>4;
  const long row0 = (long)blockIdx.x*128;
  const int  rloc0 = wv*32 + l15;

  // cooperative sDir staging (waves 2,3); consumed only after barriers
  if (tid >= 128){
    int t = tid - 128;                 // 0..127, one edge each
    long e3 = (row0 + t)*3;
    float d0 = dirv[e3+0], d1 = dirv[e3+1], d2 = dirv[e3+2];
    *(float4*)&sDir[t*4] = (float4){d0,d1,d2,0.f};
  }
  // wave-private staging: own 32 edges (same-wave LDS ordering, no barrier)
  if (lane < 32){
    int el = wv*32 + lane; long e = row0 + el;
    sE[el] = esrc[e]; sD[el] = edst[e]; sSw[el] = swv[e];
  }
  {
    const float* src = rbG + (row0 + wv*32)*NBASIS;
    *(float4*)&sRb[wv*512 + lane*8    ] = *(const float4*)(src + lane*8);
    *(float4*)&sRb[wv*512 + lane*8 + 4] = *(const float4*)(src + lane*8 + 4);
  }

  // ---- mij phase: wave computes own 32 edges, cols {d,d+1} per lane ------
  // mij = ai[src]*ai[dst]*(rb@radW + radB)*sw -> sH rows (bf16) + xi segsum
  const int d = lane*2;
  {
    float2 rw[NBASIS];
    #pragma unroll
    for (int j=0;j<NBASIS;j++) rw[j] = *(const float2*)(radW + j*DIM + d);
    float2 rBv = *(const float2*)(radB + d);
    float sx=0.f, sy=0.f;
    int cur = sE[wv*32];
    for (int i=0;i<32;i++){
      int el = wv*32 + i;
      int n = sE[el];
      if (n != cur){                       // wave-uniform branch
        atomicAdd(&xiG[(long)cur*DIM+d  ], sx);
        atomicAdd(&xiG[(long)cur*DIM+d+1], sy);
        sx=0.f; sy=0.f; cur=n;
      }
      bf16x2 as_ = *(const bf16x2*)(ai + (long)n*DIM + d);
      bf16x2 ad_ = *(const bf16x2*)(ai + (long)sD[el]*DIM + d);
      float a0=0.f, a1=0.f;
      #pragma unroll
      for (int j=0;j<NBASIS;j++){
        float rv = sRb[el*NBASIS+j];
        a0 += rv*rw[j].x; a1 += rv*rw[j].y;
      }
      float sw_ = sSw[el];
      float m0 = (float)as_[0]*(float)ad_[0]*(a0+rBv.x)*sw_;
      float m1 = (float)as_[1]*(float)ad_[1]*(a1+rBv.y)*sw_;
      bf16x2 m; m[0]=(__bf16)m0; m[1]=(__bf16)m1;
      *(bf16x2*)&sH[el*LDT + d] = m;
      sx += m0; sy += m1;
    }
    atomicAdd(&xiG[(long)cur*DIM+d  ], sx);
    atomicAdd(&xiG[(long)cur*DIM+d+1], sy);
  }

  // MFMA A-fragments from own sH rows (same-wave ordering, no barrier)
  bf16x8 fb[2][4];
  #pragma unroll
  for (int kc=0;kc<4;kc++){
    fb[0][kc] = *(bf16x8*)&sH[(rloc0   )*LDT + kc*32 + quad*8];
    fb[1][kc] = *(bf16x8*)&sH[(rloc0+16)*LDT + kc*32 + quad*8];
  }
  float swr[2];
  if constexpr (WITH_R){ swr[0]=sSw[rloc0]; swr[1]=sSw[rloc0+16]; }

  f32x4 acc[2][8];
  bf16x8 pre[4];
  float eF[2];

  auto preload = [&](const __bf16* __restrict__ Wz, int half){
    #pragma unroll
    for (int it=0; it<4; ++it)
      pre[it] = *(const bf16x8*)(Wz + (long)(half*1024 + it*256 + tid)*8);
  };
  auto writePre = [&](int b){
    #pragma unroll
    for (int it=0; it<4; ++it)
      *(bf16x8*)&sW[b][(it*256+tid)*8] = pre[it];
  };
  auto zacc = [&](){
    #pragma unroll
    for (int mi=0;mi<2;++mi)
      #pragma unroll
      for (int ni=0;ni<8;++ni) acc[mi][ni]=(f32x4){0.f,0.f,0.f,0.f};
  };
  auto mfmaB = [&](int b, int half){
    #pragma unroll
    for (int k2=0;k2<2;k2++){
      int kc = half*2 + k2;
      #pragma unroll
      for (int ni=0;ni<8;ni++){
        bf16x8 w = *(bf16x8*)&sW[b][(k2*512 + ni*64 + lane)*8];
        acc[0][ni]=mfma16(w,fb[0][kc],acc[0][ni]);
        acc[1][ni]=mfma16(w,fb[1][kc],acc[1][ni]);
      }
    }
  };
  auto mfmaH = [&](int b, int half){
    #pragma unroll
    for (int k2=0;k2<2;k2++){
      int kc = half*2 + k2;
      bf16x8 h0=*(bf16x8*)&sH[(rloc0   )*LDT + kc*32 + quad*8];
      bf16x8 h1=*(bf16x8*)&sH[(rloc0+16)*LDT + kc*32 + quad*8];
      #pragma unroll
      for (int ni=0;ni<8;ni++){
        bf16x8 w = *(bf16x8*)&sW[b][(k2*512 + ni*64 + lane)*8];
        acc[0][ni]=mfma16(w,h0,acc[0][ni]);
        acc[1][ni]=mfma16(w,h1,acc[1][ni]);
      }
    }
  };
  auto fEpi = [&](){
    float fb2v = Fb2[0];
    #pragma unroll
    for (int mi=0;mi<2;++mi){
      float p = 0.f;
      #pragma unroll
      for (int ni=0;ni<8;++ni){
        int n0 = ni*16 + quad*4;
        float4 bb = *(const float4*)(Fb1 + n0);
        float4 w2 = *(const float4*)(FW2v + n0);
        p += silu_f(acc[mi][ni][0]+bb.x)*w2.x;
        p += silu_f(acc[mi][ni][1]+bb.y)*w2.y;
        p += silu_f(acc[mi][ni][2]+bb.z)*w2.z;
        p += silu_f(acc[mi][ni][3]+bb.w)*w2.w;
      }
      p += __shfl_xor(p,16);
      p += __shfl_xor(p,32);
      eF[mi] = p + fb2v;
    }
  };
  auto hEpi = [&](const float* __restrict__ b1){
    #pragma unroll
    for (int mi=0;mi<2;++mi){
      int rl = wv*32 + mi*16 + l15;
      #pragma unroll
      for (int ni=0;ni<8;++ni){
        int n0 = ni*16 + quad*4;
        float4 bb = *(const float4*)(b1 + n0);
        bf16x4 h;
        h[0]=(__bf16)silu_f(acc[mi][ni][0]+bb.x);
        h[1]=(__bf16)silu_f(acc[mi][ni][1]+bb.y);
        h[2]=(__bf16)silu_f(acc[mi][ni][2]+bb.z);
        h[3]=(__bf16)silu_f(acc[mi][ni][3]+bb.w);
        *(bf16x4*)&sH[rl*LDT + n0] = h;
      }
    }
  };
  auto outLDS = [&](const float* __restrict__ b2, const float* mul){
    #pragma unroll
    for (int mi=0;mi<2;++mi){
      int rl = wv*32 + mi*16 + l15;
      #pragma unroll
      for (int ni=0;ni<8;++ni){
        int n0 = ni*16 + quad*4;
        float4 bb = *(const float4*)(b2 + n0);
        bf16x4 o;
        o[0]=(__bf16)((acc[mi][ni][0]+bb.x)*mul[mi]);
        o[1]=(__bf16)((acc[mi][ni][1]+bb.y)*mul[mi]);
        o[2]=(__bf16)((acc[mi][ni][2]+bb.z)*mul[mi]);
        o[3]=(__bf16)((acc[mi][ni][3]+bb.w)*mul[mi]);
        *(bf16x4*)&sH[rl*LDT + n0] = o;
      }
    }
  };
  // wave wv reduces its OWN edges [32wv,32wv+32) over all 128 cols.
  auto reduceFi = [&](){
    float a0=0.f,a1=0.f,a2=0.f,a3=0.f,a4=0.f,a5=0.f;
    int cur = sE[wv*32];
    for (int i=0;i<32;i++){
      int e = wv*32+i;
      int n = sE[e];
      if (n != cur){                    // wave-uniform
        long b = (long)cur*DIM + d;
        atomicAdd(&fiG[0L*NFE + b  ], a0);
        atomicAdd(&fiG[0L*NFE + b+1], a3);
        atomicAdd(&fiG[1L*NFE + b  ], a1);
        atomicAdd(&fiG[1L*NFE + b+1], a4);
        atomicAdd(&fiG[2L*NFE + b  ], a2);
        atomicAdd(&fiG[2L*NFE + b+1], a5);
        a0=a1=a2=a3=a4=a5=0.f; cur=n;
      }
      bf16x2 v = *(bf16x2*)&sH[e*LDT + d];
      float vx=(float)v[0], vy=(float)v[1];
      float4 dv = *(float4*)&sDir[e*4];  // broadcast b128
      a0+=vx*dv.x; a1+=vx*dv.y; a2+=vx*dv.z;
      a3+=vy*dv.x; a4+=vy*dv.y; a5+=vy*dv.z;
    }
    long b = (long)cur*DIM + d;
    atomicAdd(&fiG[0L*NFE + b  ], a0);
    atomicAdd(&fiG[0L*NFE + b+1], a3);
    atomicAdd(&fiG[1L*NFE + b  ], a1);
    atomicAdd(&fiG[1L*NFE + b+1], a4);
    atomicAdd(&fiG[2L*NFE + b  ], a2);
    atomicAdd(&fiG[2L*NFE + b+1], a5);
  };
  auto reducePhi = [&](){
    float a0=0.f,a1=0.f;
    int cur = sE[wv*32];
    for (int i=0;i<32;i++){
      int e = wv*32+i;
      int n = sE[e];
      if (n != cur){
        atomicAdd(&phiG[(long)cur*DIM + d  ], a0);
        atomicAdd(&phiG[(long)cur*DIM + d+1], a1);
        a0=a1=0.f; cur=n;
      }
      bf16x2 v = *(bf16x2*)&sH[e*LDT + d];
      a0 += (float)v[0]; a1 += (float)v[1];
    }
    atomicAdd(&phiG[(long)cur*DIM + d  ], a0);
    atomicAdd(&phiG[(long)cur*DIM + d+1], a1);
  };

  // ------- r18 ping-pong pipeline (reg staging, 1 barrier per phase) ------
  preload(FW1z,0); writePre(0);
  __syncthreads();                  // B0 + sDir published
  preload(FW1z,1);
  zacc(); mfmaB(0,0);
  writePre(1);
  __syncthreads();                  // B1 published
  preload(fW1z,0);
  mfmaB(1,1);
  writePre(0);
  __syncthreads();
  preload(fW1z,1);
  fEpi();
  zacc(); mfmaB(0,0);
  writePre(1);
  __syncthreads();
  preload(fW2z,0);
  mfmaB(1,1);
  writePre(0);
  __syncthreads();
  preload(fW2z,1);
  hEpi(fb1);
  zacc(); mfmaH(0,0);
  writePre(1);
  __syncthreads();
  if constexpr (WITH_R) preload(rW1z,0);
  mfmaH(1,1);
  outLDS(fb2, eF);                  // ef -> own sH rows
  reduceFi();                       // wave-local: fi += ef*dir

  if constexpr (WITH_R){
    writePre(0);
    __syncthreads();
    preload(rW1z,1);
    zacc(); mfmaB(0,0);
    writePre(1);
    __syncthreads();
    preload(rW2z,0);
    mfmaB(1,1);
    writePre(0);
    __syncthreads();
    preload(rW2z,1);
    hEpi(rb1);
    zacc(); mfmaH(0,0);
    writePre(1);
    __syncthreads();
    mfmaH(1,1);
    outLDS(rb2, swr);               // ephi -> own sH rows
    reducePhi();                    // wave-local: phi += ephi
  }
}

// ===========================================================================
// Fused node kernel (runs AFTER mlp_edge, reads post-segsum xi):
//   R-MLP, u-MLP (Rv/uv stay in regs) -> di/scal/xi update -> a-MLP(l+1).
// 64 nodes/block (4 waves x 16 rows), 157 blocks.
// ===========================================================================
__global__ __launch_bounds__(256,2) void node_fused(
    const float* __restrict__ X,
    const __bf16* __restrict__ RW1z, const float* __restrict__ Rb1,
    const __bf16* __restrict__ RW2z, const float* __restrict__ Rb2,
    const __bf16* __restrict__ uW1z, const float* __restrict__ ub1,
    const __bf16* __restrict__ uW2z, const float* __restrict__ ub2,
    const __bf16* __restrict__ aW1z, const float* __restrict__ ab1,
    const __bf16* __restrict__ aW2z, const float* __restrict__ ab2,
    float* __restrict__ fi, float* __restrict__ di,
    float* __restrict__ phi, float* __restrict__ xi,
    __bf16* __restrict__ ai, float* __restrict__ out, int layer)
{
  __shared__ __bf16 sH[64*LDT];    // 17408 B, wave-private 16-row slices
  const int tid=threadIdx.x, lane=tid&63, wv=tid>>6, l15=lane&15, quad=lane>>4;
  const long rA = (long)blockIdx.x*64 + wv*16 + l15;
  const bool okA = rA < N_NODES;
  const int rl = wv*16 + l15;

  bf16x8 fa[4];
  #pragma unroll
  for (int kc=0;kc<4;kc++){
    int kb=kc*32+quad*8;
    bf16x8 a;
    #pragma unroll
    for (int i=0;i<8;i++) a[i]=(__bf16)0.f;
    if (okA){
      float4 u0 = *(const float4*)(X + rA*DIM + kb);
      float4 u1 = *(const float4*)(X + rA*DIM + kb + 4);
      a[0]=(__bf16)u0.x;a[1]=(__bf16)u0.y;a[2]=(__bf16)u0.z;a[3]=(__bf16)u0.w;
      a[4]=(__bf16)u1.x;a[5]=(__bf16)u1.y;a[6]=(__bf16)u1.z;a[7]=(__bf16)u1.w;
    }
    fa[kc]=a;
  }

  f32x4 acc[8];
  auto zacc = [&](){
    #pragma unroll
    for (int ni=0;ni<8;++ni) acc[ni]=(f32x4){0.f,0.f,0.f,0.f};
  };
  auto gemmA = [&](const __bf16* __restrict__ Wz, const bf16x8* f){
    #pragma unroll
    for (int kc=0;kc<4;kc++){
      #pragma unroll
      for (int ni=0;ni<8;ni++){
        bf16x8 w = *(const bf16x8*)(Wz + (long)(kc*512 + ni*64 + lane)*8);
        acc[ni]=mfma16(w,f[kc],acc[ni]);
      }
    }
  };
  auto gemmH = [&](const __bf16* __restrict__ Wz){
    #pragma unroll
    for (int kc=0;kc<4;kc++){
      bf16x8 h0=*(bf16x8*)&sH[rl*LDT + kc*32 + quad*8];
      #pragma unroll
      for (int ni=0;ni<8;ni++){
        bf16x8 w = *(const bf16x8*)(Wz + (long)(kc*512 + ni*64 + lane)*8);
        acc[ni]=mfma16(w,h0,acc[ni]);
      }
    }
  };
  auto hEpi = [&](const float* __restrict__ b1){
    #pragma unroll
    for (int ni=0;ni<8;++ni){
      int n0 = ni*16 + quad*4;
      float4 bb = *(const float4*)(b1 + n0);
      bf16x4 h;
      h[0]=(__bf16)silu_f(acc[ni][0]+bb.x);
      h[1]=(__bf16)silu_f(acc[ni][1]+bb.y);
      h[2]=(__bf16)silu_f(acc[ni][2]+bb.z);
      h[3]=(__bf16)silu_f(acc[ni][3]+bb.w);
      *(bf16x4*)&sH[rl*LDT + n0] = h;
    }
  };

  f32x4 Rv4[8], Uv4[8];
  zacc(); gemmA(RW1z, fa); hEpi(Rb1);
  zacc(); gemmH(RW2z);
  #pragma unroll
  for (int ni=0;ni<8;++ni) Rv4[ni]=acc[ni];
  zacc(); gemmA(uW1z, fa); hEpi(ub1);
  zacc(); gemmH(uW2z);
  #pragma unroll
  for (int ni=0;ni<8;++ni) Uv4[ni]=acc[ni];

  // ---- update: di = (l? phi*di:0) + Rv*fi; sc = sum_k fi*di;
  //      nx = xi - uv*sc; write xi/out, phi=0, nx -> sH for a-MLP ---------
  if (okA){
    #pragma unroll
    for (int ni=0;ni<8;++ni){
      int n0 = ni*16 + quad*4;
      long idx = rA*DIM + n0;
      float4 rb2v = *(const float4*)(Rb2 + n0);
      float4 ub2v = *(const float4*)(ub2 + n0);
      float4 f0 = *(const float4*)(fi + idx);
      float4 f1 = *(const float4*)(fi + NFE + idx);
      float4 f2 = *(const float4*)(fi + 2L*NFE + idx);
      float4 xv = *(const float4*)(X + idx);
      float4 ph = (layer>0) ? *(const float4*)(phi + idx) : (float4){0,0,0,0};
      float4 e0 = (layer>0) ? *(const float4*)(di + idx)          : (float4){0,0,0,0};
      float4 e1 = (layer>0) ? *(const float4*)(di + NFE + idx)    : (float4){0,0,0,0};
      float4 e2 = (layer>0) ? *(const float4*)(di + 2L*NFE + idx) : (float4){0,0,0,0};
      float4 nd0, nd1, nd2, nx;
      #pragma unroll
      for (int j=0;j<4;++j){
        float Rvv = Rv4[ni][j] + ((const float*)&rb2v)[j];
        float uvv = Uv4[ni][j] + ((const float*)&ub2v)[j];
        float d0v = ((const float*)&ph)[j]*((const float*)&e0)[j] + Rvv*((const float*)&f0)[j];
        float d1v = ((const float*)&ph)[j]*((const float*)&e1)[j] + Rvv*((const float*)&f1)[j];
        float d2v = ((const float*)&ph)[j]*((const float*)&e2)[j] + Rvv*((const float*)&f2)[j];
        float sc = ((const float*)&f0)[j]*d0v + ((const float*)&f1)[j]*d1v
                 + ((const float*)&f2)[j]*d2v;
        ((float*)&nd0)[j]=d0v; ((float*)&nd1)[j]=d1v; ((float*)&nd2)[j]=d2v;
        ((float*)&nx)[j] = ((const float*)&xv)[j] - uvv*sc;
      }
      *(float4*)(di + idx)          = nd0;
      *(float4*)(di + NFE + idx)    = nd1;
      *(float4*)(di + 2L*NFE + idx) = nd2;
      if (layer == 2){
        *(float4*)(out + idx) = nx;
      } else {
        *(float4*)(xi + idx) = nx;
        *(float4*)(phi + idx) = (float4){0,0,0,0};
        bf16x4 h;
        h[0]=(__bf16)nx.x; h[1]=(__bf16)nx.y;
        h[2]=(__bf16)nx.z; h[3]=(__bf16)nx.w;
        *(bf16x4*)&sH[rl*LDT + n0] = h;
      }
    }
  }

  if (layer < 2){
    bf16x8 fa2[4];
    #pragma unroll
    for (int kc=0;kc<4;kc++)
      fa2[kc] = *(bf16x8*)&sH[rl*LDT + kc*32 + quad*8];
    zacc(); gemmA(aW1z, fa2); hEpi(ab1);
    zacc(); gemmH(aW2z);
    if (okA){
      #pragma unroll
      for (int ni=0;ni<8;++ni){
        int n0 = ni*16 + quad*4;
        float4 bb = *(const float4*)(ab2 + n0);
        bf16x4 o;
        o[0]=(__bf16)(acc[ni][0]+bb.x);
        o[1]=(__bf16)(acc[ni][1]+bb.y);
        o[2]=(__bf16)(acc[ni][2]+bb.z);
        o[3]=(__bf16)(acc[ni][3]+bb.w);
        *(bf16x4*)(ai + rA*DIM + n0) = o;
      }
    }
  }
}

// ===========================================================================
// Node MLP a (layer 0 only): 1-wave blocks, 16 rows each -> 625 blocks.
// ===========================================================================
__global__ __launch_bounds__(64,4) void mlp_a(
    const float* __restrict__ X,
    const __bf16* __restrict__ W1z, const float* __restrict__ b1,
    const __bf16* __restrict__ W2z, const float* __restrict__ b2,
    __bf16* __restrict__ Y)
{
  __shared__ __bf16 sH[16*LDT];
  const int lane=threadIdx.x, l15=lane&15, quad=lane>>4;
  const long row0=(long)blockIdx.x*16;
  const long rA=row0+l15;

  bf16x8 fa[4];
  #pragma unroll
  for (int kc=0;kc<4;kc++){
    int kb=kc*32+quad*8;
    float4 u0 = *(const float4*)(X + rA*DIM + kb);
    float4 u1 = *(const float4*)(X + rA*DIM + kb + 4);
    bf16x8 a;
    a[0]=(__bf16)u0.x;a[1]=(__bf16)u0.y;a[2]=(__bf16)u0.z;a[3]=(__bf16)u0.w;
    a[4]=(__bf16)u1.x;a[5]=(__bf16)u1.y;a[6]=(__bf16)u1.z;a[7]=(__bf16)u1.w;
    fa[kc]=a;
  }

  f32x4 acc[8];
  #pragma unroll
  for (int ni=0;ni<8;++ni) acc[ni]=(f32x4){0.f,0.f,0.f,0.f};
  #pragma unroll
  for (int kc=0;kc<4;kc++){
    #pragma unroll
    for (int ni=0;ni<8;ni++){
      bf16x8 w = *(const bf16x8*)(W1z + (long)(kc*512 + ni*64 + lane)*8);
      acc[ni]=mfma16(w,fa[kc],acc[ni]);
    }
  }
  #pragma unroll
  for (int ni=0;ni<8;++ni){
    int n0 = ni*16 + quad*4;
    float4 bb = *(const float4*)(b1 + n0);
    bf16x4 h;
    h[0]=(__bf16)silu_f(acc[ni][0]+bb.x);
    h[1]=(__bf16)silu_f(acc[ni][1]+bb.y);
    h[2]=(__bf16)silu_f(acc[ni][2]+bb.z);
    h[3]=(__bf16)silu_f(acc[ni][3]+bb.w);
    *(bf16x4*)&sH[l15*LDT + n0] = h;
  }
  #pragma unroll
  for (int ni=0;ni<8;++ni) acc[ni]=(f32x4){0.f,0.f,0.f,0.f};
  #pragma unroll
  for (int kc=0;kc<4;kc++){
    bf16x8 h0=*(bf16x8*)&sH[l15*LDT + kc*32 + quad*8];
    #pragma unroll
    for (int ni=0;ni<8;ni++){
      bf16x8 w = *(const bf16x8*)(W2z + (long)(kc*512 + ni*64 + lane)*8);
      acc[ni]=mfma16(w,h0,acc[ni]);
    }
  }
  #pragma unroll
  for (int ni=0;ni<8;++ni){
    int n0 = ni*16 + quad*4;
    float4 bb = *(const float4*)(b2 + n0);
    bf16x4 o;
    o[0]=(__bf16)(acc[ni][0]+bb.x);
    o[1]=(__bf16)(acc[ni][1]+bb.y);
    o[2]=(__bf16)(acc[ni][2]+bb.z);
    o[3]=(__bf16)(acc[ni][3]+bb.w);
    *(bf16x4*)(Y + rA*DIM + n0) = o;
  }
}

// ===========================================================================
// One-shot setup: weight swizzle + node init + edge geometry
// ===========================================================================
__global__ __launch_bounds__(256) void setup_all(
    WPtrs wp, __bf16* __restrict__ wt,
    const int* __restrict__ species, const float* __restrict__ spW,
    const float* __restrict__ spB, float* __restrict__ xi, float* __restrict__ fi,
    float* __restrict__ phi,
    const float* __restrict__ dist, const float* __restrict__ vec,
    const float* __restrict__ swv, float* __restrict__ dir, float* __restrict__ rb)
{
  const int b = blockIdx.x, tid = threadIdx.x;
  if (b < 33){
    int t = b/3, l = b%3;
    const float* src = wp.p[t] + (size_t)l*16384;
    __bf16* out = wt + (size_t)b*16384;
    for (int it=0; it<8; ++it){
      int fi_ = it*256 + tid;
      int kc = fi_>>9, ni = (fi_>>6)&7, lane = fi_&63;
      int n  = ni*16 + (lane&15);
      int k0 = kc*32 + (lane>>4)*8;
      bf16x8 v;
      #pragma unroll
      for (int j=0;j<8;++j) v[j] = (__bf16)src[(k0+j)*DIM + n];
      *(bf16x8*)(out + (size_t)fi_*8) = v;
    }
  } else if (b < 33 + 5000){
    int idx = (b-33)*256 + tid;     // < N*128
    int n = idx >> 7, d = idx & 127;
    xi[idx] = spW[species[n]*DIM + d] + spB[d];
    phi[idx] = 0.f;
    fi[idx] = 0.f;                  // plane 0
    fi[NFE + idx] = 0.f;            // plane 1
    fi[2L*NFE + idx] = 0.f;         // plane 2
  } else {
    int e = (b-5033)*256 + tid;
    if (e < N_EDGES){
      float d = dist[e];
      float s = swv[e];
      float inv = s / d;
      dir[e*3+0] = vec[e*3+0]*inv;
      dir[e*3+1] = vec[e*3+1]*inv;
      dir[e*3+2] = vec[e*3+2]*inv;
      const float eta = (16.0f/5.0f)*(16.0f/5.0f);
      #pragma unroll
      for (int j=0;j<NBASIS;j++){
        float c = (float)j * (5.0f/15.0f);
        float t2 = d - c;
        rb[e*NBASIS + j] = __expf(-eta*t2*t2);
      }
    }
  }
}

extern "C" void kernel_launch(void* const* d_in, const int* in_sizes, int n_in,
                              void* d_out, int out_size, void* d_ws, size_t ws_size,
                              hipStream_t stream) {
  const int*   species = (const int*)  d_in[0];
  const int*   esrc    = (const int*)  d_in[1];
  const int*   edst    = (const int*)  d_in[2];
  const float* dist    = (const float*)d_in[3];
  const float* vec     = (const float*)d_in[4];
  const float* swv     = (const float*)d_in[5];
  const float* spW     = (const float*)d_in[6];
  const float* spB     = (const float*)d_in[7];
  const float* radW    = (const float*)d_in[8];
  const float* radB    = (const float*)d_in[9];
  const float* aW1=(const float*)d_in[10], *aB1=(const float*)d_in[11], *aW2=(const float*)d_in[12], *aB2=(const float*)d_in[13];
  const float* FW1=(const float*)d_in[14], *FB1=(const float*)d_in[15], *FW2=(const float*)d_in[16], *FB2=(const float*)d_in[17];
  const float* fW1=(const float*)d_in[18], *fB1=(const float*)d_in[19], *fW2=(const float*)d_in[20], *fB2=(const float*)d_in[21];
  const float* RW1=(const float*)d_in[22], *RB1=(const float*)d_in[23], *RW2=(const float*)d_in[24], *RB2=(const float*)d_in[25];
  const float* rW1=(const float*)d_in[26], *rB1=(const float*)d_in[27], *rW2=(const float*)d_in[28], *rB2=(const float*)d_in[29];
  const float* uW1=(const float*)d_in[30], *uB1=(const float*)d_in[31], *uW2=(const float*)d_in[32], *uB2=(const float*)d_in[33];

  const long NF = (long)N_NODES*DIM;      // 1,280,000
  float* ws   = (float*)d_ws;
  float* xi   = ws;
  float* phi  = xi   + NF;
  float* fi   = phi  + NF;                // 3 planes of NF
  float* di   = fi   + 3*NF;              // 3 planes of NF
  float* dir  = di   + 3*NF;
  float* rb   = dir  + 3L*N_EDGES;
  char* bp = (char*)(rb + 16L*N_EDGES);
  size_t off = ((size_t)(bp - (char*)d_ws) + 15) & ~(size_t)15;
  __bf16* ai   = (__bf16*)((char*)d_ws + off);
  __bf16* wt   = ai + NF;                 // 33 x 128x128 bf16 (swizzled)

  // swizzled bf16 weights: tensor order a1,a2,F1,f1,f2,R1,R2,r1,r2,u1,u2
  WPtrs wp;
  wp.p[0]=aW1; wp.p[1]=aW2; wp.p[2]=FW1; wp.p[3]=fW1; wp.p[4]=fW2;
  wp.p[5]=RW1; wp.p[6]=RW2; wp.p[7]=rW1; wp.p[8]=rW2; wp.p[9]=uW1; wp.p[10]=uW2;

  // one-shot setup: 33 convert + 5000 init + 625 geom = 5658 blocks
  setup_all<<<5658, 256, 0, stream>>>(wp, wt,
                                      species, spW, spB, xi, fi, phi,
                                      dist, vec, swv, dir, rb);

  #define WT(t,l) (wt + (size_t)((t)*3+(l))*16384)

  // a-MLP for layer 0 (later layers fused into node_fused)
  mlp_a<<<N_NODES/16, 64, 0, stream>>>(xi, WT(0,0), aB1, WT(1,0), aB2, ai);

  const int edgeB = N_EDGES/128;              // 1250
  const int nodeB = (N_NODES + 63)/64;        // 157

  for (int l=0;l<3;l++){
    const long bo = (long)l*DIM;

    // edge kernel: mij (LDS) + xi segsum + F/f[/r] MLPs + fi/phi atomics
    if (l == 0)
      mlp_edge<false><<<edgeB, 256, 0, stream>>>(
          ai, esrc, edst, swv, rb,
          radW + (long)l*NBASIS*DIM, radB + bo, dir,
          WT(3,l), fB1+bo, WT(4,l), fB2+bo,
          WT(2,l), FB1+bo, FW2+(long)l*DIM, FB2+l,
          nullptr, nullptr, nullptr, nullptr,
          xi, fi, phi);
    else
      mlp_edge<true><<<edgeB, 256, 0, stream>>>(
          ai, esrc, edst, swv, rb,
          radW + (long)l*NBASIS*DIM, radB + bo, dir,
          WT(3,l), fB1+bo, WT(4,l), fB2+bo,
          WT(2,l), FB1+bo, FW2+(long)l*DIM, FB2+l,
          WT(7,l), rB1+bo, WT(8,l), rB2+bo,
          xi, fi, phi);

    // fused node kernel: R,u MLPs + di/scal/xi update + a-MLP(l+1)
    int ln = (l < 2) ? (l+1) : 0;   // a-weights for next layer (unused if l==2)
    node_fused<<<nodeB, 256, 0, stream>>>(
        xi,
        WT(5,l), RB1+bo, WT(6,l), RB2+bo,
        WT(9,l), uB1+bo, WT(10,l), uB2+bo,
        WT(0,ln), aB1+(long)ln*DIM, WT(1,ln), aB2+(long)ln*DIM,
        fi, di, phi, xi, ai, (float*)d_out, l);
  }
}

// Round 5
// 490.365 us; speedup vs baseline: 1.2497x; 1.2497x over previous
//
#include <hip/hip_runtime.h>
#include <hip/hip_bf16.h>

#define N_NODES 10000
#define N_EDGES 160000
#define DIM     128
#define NBASIS  16
#define LDT     136   // LDS row stride (bf16); 272B row, 16B aligned
#define NFE     (N_NODES*DIM)   // 1,280,000 elements per plane

typedef __bf16 bf16x8 __attribute__((ext_vector_type(8)));
typedef __bf16 bf16x4 __attribute__((ext_vector_type(4)));
typedef __bf16 bf16x2 __attribute__((ext_vector_type(2)));
typedef float  f32x4  __attribute__((ext_vector_type(4)));

__device__ __forceinline__ float silu_f(float x){
  return x * (1.0f / (1.0f + __expf(-x)));
}
__device__ __forceinline__ f32x4 mfma16(bf16x8 a, bf16x8 b, f32x4 c){
  return __builtin_amdgcn_mfma_f32_16x16x32_bf16(a,b,c,0,0,0);
}

// Swizzled weight layout: frag (kc,ni,lane) at Wz[(kc*512+ni*64+lane)*8+j].
// Design log: r9 LDS weights; r10 operand-swap; r11 fused mij+segsum;
// r12 reg radW; r13 node-MLP merge; r16/r17 in-kernel fi/phi reduction;
// r18 ping-pong sW reg-staging (1 barrier/phase) -> 504us (mlp_layer 90us).
// r19 FAILED (694): (256,4) on unified VGPR/AGPR file -> 64V, spills.
// r20 FAILED (641): direct-global weights latency-serialize.
// r21 FAILED (531): global_load_lds staging; vmcnt(0) drain at barriers.
// r22 FAILED (613): (a) mij-in-edge-kernel puts a serial gather chain at
// every block head at 2 blk/CU (+37us/dispatch); (b) R/u GEMMs in a
// 157-block kernel lose the r13 overlap (~60us/dispatch). Also resolved:
// occupancy is DOUBLE-capped -- 128 VGPR + 64 AGPR = 192 unified regs
// (2 waves/SIMD) AND 70KB LDS (2 blocks/CU); that's why small-LDS r15/r17
// never went to 3 blocks. Breaking past needs both cut at once: not worth
// the spill risk (r19).
// r23: r18 restored verbatim (mij_segsum + combined mlp_layer). Only safe
// deltas kept: node_update (+) next-layer mlp_a fused into node_upd_a
// (one wave: update in regs -> nx -> sH -> a-GEMM; kills one xi
// round-trip, 3 launches; layer 2 drops dead di/xi/phi stores), and
// stride-4 sDir (1x ds_read_b128 vs 3x b32 in reduceFi).
// r8 lesson: smaller edge tiles double chip-wide weight traffic.
// r6 lesson (re-learned r19): never force min-waves below live state.

struct WPtrs { const float* p[11]; };

// ===========================================================================
// Combined per-layer MLP dispatch.
//  blocks [0, nodeB):   R- and u-MLPs on xi (64 rows/block, 4 indep waves)
//  blocks [nodeB, ...): edge MLPs on mij (128 edges/block) + wave-local
//                       segment reduction of ef*dir -> fi planes, ephi -> phi.
// ===========================================================================
template<bool WITH_R>
__global__ __launch_bounds__(256,2) void mlp_layer(
    int nodeB,
    const __bf16* __restrict__ mij,
    const int*    __restrict__ esrc, const float* __restrict__ dirv,
    const __bf16* __restrict__ fW1z, const float* __restrict__ fb1,
    const __bf16* __restrict__ fW2z, const float* __restrict__ fb2,
    const __bf16* __restrict__ FW1z, const float* __restrict__ Fb1,
    const float*  __restrict__ FW2v, const float* __restrict__ Fb2,
    const __bf16* __restrict__ rW1z, const float* __restrict__ rb1,
    const __bf16* __restrict__ rW2z, const float* __restrict__ rb2,
    const float*  __restrict__ swv,
    float* __restrict__ fiG, float* __restrict__ phiG,
    const float* __restrict__ X,
    const __bf16* __restrict__ RW1z, const float* __restrict__ Rb1,
    const __bf16* __restrict__ RW2z, const float* __restrict__ Rb2,
    const __bf16* __restrict__ uW1z, const float* __restrict__ ub1,
    const __bf16* __restrict__ uW2z, const float* __restrict__ ub2,
    float* __restrict__ Rv, float* __restrict__ uv)
{
  __shared__ __bf16 sH[128*LDT];   // 34816 B
  __shared__ __bf16 sW[2][8192];   // 32768 B (ping-pong)
  __shared__ int    sE[128];       //   512 B
  __shared__ float  sDir[128*4];   //  2048 B  (total 70144 -> 2 blocks/CU)
  const int tid=threadIdx.x, lane=tid&63, wv=tid>>6, l15=lane&15, quad=lane>>4;

  if ((int)blockIdx.x < nodeB){
    // ---------------- node path: R and u MLPs, 16 rows per wave -----------
    const long row0n = (long)blockIdx.x*64 + wv*16;
    const long rA = row0n + l15;
    const bool okA = rA < N_NODES;

    bf16x8 fa[4];
    #pragma unroll
    for (int kc=0;kc<4;kc++){
      int kb=kc*32+quad*8;
      bf16x8 a;
      #pragma unroll
      for (int i=0;i<8;i++) a[i]=(__bf16)0.f;
      if (okA){
        float4 u0 = *(const float4*)(X + rA*DIM + kb);
        float4 u1 = *(const float4*)(X + rA*DIM + kb + 4);
        a[0]=(__bf16)u0.x;a[1]=(__bf16)u0.y;a[2]=(__bf16)u0.z;a[3]=(__bf16)u0.w;
        a[4]=(__bf16)u1.x;a[5]=(__bf16)u1.y;a[6]=(__bf16)u1.z;a[7]=(__bf16)u1.w;
      }
      fa[kc]=a;
    }

    f32x4 acc[8];
    auto zacc = [&](){
      #pragma unroll
      for (int ni=0;ni<8;++ni) acc[ni]=(f32x4){0.f,0.f,0.f,0.f};
    };
    auto gemmA = [&](const __bf16* __restrict__ Wz){
      #pragma unroll
      for (int kc=0;kc<4;kc++){
        #pragma unroll
        for (int ni=0;ni<8;ni++){
          bf16x8 w = *(const bf16x8*)(Wz + (long)(kc*512 + ni*64 + lane)*8);
          acc[ni]=mfma16(w,fa[kc],acc[ni]);
        }
      }
    };
    auto gemmH = [&](const __bf16* __restrict__ Wz){
      #pragma unroll
      for (int kc=0;kc<4;kc++){
        bf16x8 h0=*(bf16x8*)&sH[(wv*16+l15)*LDT + kc*32 + quad*8];
        #pragma unroll
        for (int ni=0;ni<8;ni++){
          bf16x8 w = *(const bf16x8*)(Wz + (long)(kc*512 + ni*64 + lane)*8);
          acc[ni]=mfma16(w,h0,acc[ni]);
        }
      }
    };
    auto hEpi = [&](const float* __restrict__ b1){
      #pragma unroll
      for (int ni=0;ni<8;++ni){
        int n0 = ni*16 + quad*4;
        float4 bb = *(const float4*)(b1 + n0);
        bf16x4 h;
        h[0]=(__bf16)silu_f(acc[ni][0]+bb.x);
        h[1]=(__bf16)silu_f(acc[ni][1]+bb.y);
        h[2]=(__bf16)silu_f(acc[ni][2]+bb.z);
        h[3]=(__bf16)silu_f(acc[ni][3]+bb.w);
        *(bf16x4*)&sH[(wv*16+l15)*LDT + n0] = h;
      }
    };
    auto cStoreF = [&](const float* __restrict__ b2, float* __restrict__ Y){
      if (okA){
        #pragma unroll
        for (int ni=0;ni<8;++ni){
          int n0 = ni*16 + quad*4;
          float4 bb = *(const float4*)(b2 + n0);
          float4 o;
          o.x=acc[ni][0]+bb.x; o.y=acc[ni][1]+bb.y;
          o.z=acc[ni][2]+bb.z; o.w=acc[ni][3]+bb.w;
          *(float4*)(Y + rA*DIM + n0) = o;
        }
      }
    };

    zacc(); gemmA(RW1z); hEpi(Rb1);
    zacc(); gemmH(RW2z); cStoreF(Rb2, Rv);
    zacc(); gemmA(uW1z); hEpi(ub1);
    zacc(); gemmH(uW2z); cStoreF(ub2, uv);
    return;
  }

  // ---------------- edge path: F/f[/r] MLPs on mij ------------------------
  const long row0 = (long)(blockIdx.x - nodeB)*128;
  const int  rloc0 = wv*32 + l15;
  const long rB0 = row0 + rloc0, rB1 = rB0+16;

  // stage esrc + dir (stride-4 padded) for this block's 128 edges
  if (tid < 32)  *(int4*)&sE[tid*4] = *(const int4*)(esrc + row0 + tid*4);
  if (tid >= 128){
    int t = tid - 128;                 // 0..127, one edge each
    long e3 = (row0 + t)*3;
    float d0 = dirv[e3+0], d1 = dirv[e3+1], d2 = dirv[e3+2];
    *(float4*)&sDir[t*4] = (float4){d0,d1,d2,0.f};
  }

  bf16x8 fb[2][4];
  #pragma unroll
  for (int kc=0;kc<4;kc++){
    fb[0][kc] = *(const bf16x8*)(mij + rB0*DIM + kc*32 + quad*8);
    fb[1][kc] = *(const bf16x8*)(mij + rB1*DIM + kc*32 + quad*8);
  }
  float swr[2];
  if constexpr (WITH_R){ swr[0]=swv[rB0]; swr[1]=swv[rB1]; }

  f32x4 acc[2][8];
  bf16x8 pre[4];
  float eF[2];

  auto preload = [&](const __bf16* __restrict__ Wz, int half){
    #pragma unroll
    for (int it=0; it<4; ++it)
      pre[it] = *(const bf16x8*)(Wz + (long)(half*1024 + it*256 + tid)*8);
  };
  auto writePre = [&](int b){
    #pragma unroll
    for (int it=0; it<4; ++it)
      *(bf16x8*)&sW[b][(it*256+tid)*8] = pre[it];
  };
  auto zacc = [&](){
    #pragma unroll
    for (int mi=0;mi<2;++mi)
      #pragma unroll
      for (int ni=0;ni<8;++ni) acc[mi][ni]=(f32x4){0.f,0.f,0.f,0.f};
  };
  auto mfmaB = [&](int b, int half){
    #pragma unroll
    for (int k2=0;k2<2;k2++){
      int kc = half*2 + k2;
      #pragma unroll
      for (int ni=0;ni<8;ni++){
        bf16x8 w = *(bf16x8*)&sW[b][(k2*512 + ni*64 + lane)*8];
        acc[0][ni]=mfma16(w,fb[0][kc],acc[0][ni]);
        acc[1][ni]=mfma16(w,fb[1][kc],acc[1][ni]);
      }
    }
  };
  auto mfmaH = [&](int b, int half){
    #pragma unroll
    for (int k2=0;k2<2;k2++){
      int kc = half*2 + k2;
      bf16x8 h0=*(bf16x8*)&sH[(rloc0   )*LDT + kc*32 + quad*8];
      bf16x8 h1=*(bf16x8*)&sH[(rloc0+16)*LDT + kc*32 + quad*8];
      #pragma unroll
      for (int ni=0;ni<8;ni++){
        bf16x8 w = *(bf16x8*)&sW[b][(k2*512 + ni*64 + lane)*8];
        acc[0][ni]=mfma16(w,h0,acc[0][ni]);
        acc[1][ni]=mfma16(w,h1,acc[1][ni]);
      }
    }
  };
  auto fEpi = [&](){
    float fb2v = Fb2[0];
    #pragma unroll
    for (int mi=0;mi<2;++mi){
      float p = 0.f;
      #pragma unroll
      for (int ni=0;ni<8;++ni){
        int n0 = ni*16 + quad*4;
        float4 bb = *(const float4*)(Fb1 + n0);
        float4 w2 = *(const float4*)(FW2v + n0);
        p += silu_f(acc[mi][ni][0]+bb.x)*w2.x;
        p += silu_f(acc[mi][ni][1]+bb.y)*w2.y;
        p += silu_f(acc[mi][ni][2]+bb.z)*w2.z;
        p += silu_f(acc[mi][ni][3]+bb.w)*w2.w;
      }
      p += __shfl_xor(p,16);
      p += __shfl_xor(p,32);
      eF[mi] = p + fb2v;
    }
  };
  auto hEpi = [&](const float* __restrict__ b1){
    #pragma unroll
    for (int mi=0;mi<2;++mi){
      int rl = wv*32 + mi*16 + l15;
      #pragma unroll
      for (int ni=0;ni<8;++ni){
        int n0 = ni*16 + quad*4;
        float4 bb = *(const float4*)(b1 + n0);
        bf16x4 h;
        h[0]=(__bf16)silu_f(acc[mi][ni][0]+bb.x);
        h[1]=(__bf16)silu_f(acc[mi][ni][1]+bb.y);
        h[2]=(__bf16)silu_f(acc[mi][ni][2]+bb.z);
        h[3]=(__bf16)silu_f(acc[mi][ni][3]+bb.w);
        *(bf16x4*)&sH[rl*LDT + n0] = h;
      }
    }
  };
  // MLP output (x bias x mul) -> sH (wave-private rows), bf16
  auto outLDS = [&](const float* __restrict__ b2, const float* mul){
    #pragma unroll
    for (int mi=0;mi<2;++mi){
      int rl = wv*32 + mi*16 + l15;
      #pragma unroll
      for (int ni=0;ni<8;++ni){
        int n0 = ni*16 + quad*4;
        float4 bb = *(const float4*)(b2 + n0);
        bf16x4 o;
        o[0]=(__bf16)((acc[mi][ni][0]+bb.x)*mul[mi]);
        o[1]=(__bf16)((acc[mi][ni][1]+bb.y)*mul[mi]);
        o[2]=(__bf16)((acc[mi][ni][2]+bb.z)*mul[mi]);
        o[3]=(__bf16)((acc[mi][ni][3]+bb.w)*mul[mi]);
        *(bf16x4*)&sH[rl*LDT + n0] = o;
      }
    }
  };
  // wave wv reduces its OWN edges [32wv,32wv+32) over all 128 cols.
  // Same-wave LDS write->read ordering (lgkmcnt) -- no barrier needed.
  auto reduceFi = [&](){
    const int d = lane*2;
    float a0=0.f,a1=0.f,a2=0.f,a3=0.f,a4=0.f,a5=0.f;
    int cur = sE[wv*32];
    for (int i=0;i<32;i++){
      int e = wv*32+i;
      int n = sE[e];
      if (n != cur){                    // wave-uniform
        long b = (long)cur*DIM + d;
        atomicAdd(&fiG[0L*NFE + b  ], a0);
        atomicAdd(&fiG[0L*NFE + b+1], a3);
        atomicAdd(&fiG[1L*NFE + b  ], a1);
        atomicAdd(&fiG[1L*NFE + b+1], a4);
        atomicAdd(&fiG[2L*NFE + b  ], a2);
        atomicAdd(&fiG[2L*NFE + b+1], a5);
        a0=a1=a2=a3=a4=a5=0.f; cur=n;
      }
      bf16x2 v = *(bf16x2*)&sH[e*LDT + d];
      float vx=(float)v[0], vy=(float)v[1];
      float4 dv = *(float4*)&sDir[e*4];  // broadcast b128
      a0+=vx*dv.x; a1+=vx*dv.y; a2+=vx*dv.z;
      a3+=vy*dv.x; a4+=vy*dv.y; a5+=vy*dv.z;
    }
    long b = (long)cur*DIM + d;
    atomicAdd(&fiG[0L*NFE + b  ], a0);
    atomicAdd(&fiG[0L*NFE + b+1], a3);
    atomicAdd(&fiG[1L*NFE + b  ], a1);
    atomicAdd(&fiG[1L*NFE + b+1], a4);
    atomicAdd(&fiG[2L*NFE + b  ], a2);
    atomicAdd(&fiG[2L*NFE + b+1], a5);
  };
  auto reducePhi = [&](){
    const int d = lane*2;
    float a0=0.f,a1=0.f;
    int cur = sE[wv*32];
    for (int i=0;i<32;i++){
      int e = wv*32+i;
      int n = sE[e];
      if (n != cur){
        atomicAdd(&phiG[(long)cur*DIM + d  ], a0);
        atomicAdd(&phiG[(long)cur*DIM + d+1], a1);
        a0=a1=0.f; cur=n;
      }
      bf16x2 v = *(bf16x2*)&sH[e*LDT + d];
      a0 += (float)v[0]; a1 += (float)v[1];
    }
    atomicAdd(&phiG[(long)cur*DIM + d  ], a0);
    atomicAdd(&phiG[(long)cur*DIM + d+1], a1);
  };

  // ------- ping-pong pipeline: 1 barrier per phase (publish next buf) ------
  preload(FW1z,0); writePre(0);
  __syncthreads();                  // B0 + sE/sDir published
  preload(FW1z,1);
  zacc(); mfmaB(0,0);
  writePre(1);
  __syncthreads();                  // B1 published
  preload(fW1z,0);
  mfmaB(1,1);
  writePre(0);
  __syncthreads();
  preload(fW1z,1);
  fEpi();
  zacc(); mfmaB(0,0);
  writePre(1);
  __syncthreads();
  preload(fW2z,0);
  mfmaB(1,1);
  writePre(0);
  __syncthreads();
  preload(fW2z,1);
  hEpi(fb1);
  zacc(); mfmaH(0,0);
  writePre(1);
  __syncthreads();
  if constexpr (WITH_R) preload(rW1z,0);
  mfmaH(1,1);
  outLDS(fb2, eF);                  // ef -> own sH rows
  reduceFi();                       // wave-local: fi += ef*dir

  if constexpr (WITH_R){
    writePre(0);
    __syncthreads();
    preload(rW1z,1);
    zacc(); mfmaB(0,0);
    writePre(1);
    __syncthreads();
    preload(rW2z,0);
    mfmaB(1,1);
    writePre(0);
    __syncthreads();
    preload(rW2z,1);
    hEpi(rb1);
    zacc(); mfmaH(0,0);
    writePre(1);
    __syncthreads();
    mfmaH(1,1);
    outLDS(rb2, swr);               // ephi -> own sH rows
    reducePhi();                    // wave-local: phi += ephi
  }
}

// ===========================================================================
// Node MLP a (layer 0 only): 1-wave blocks, 16 rows each -> 625 blocks.
// ===========================================================================
__global__ __launch_bounds__(64,4) void mlp_a(
    const float* __restrict__ X,
    const __bf16* __restrict__ W1z, const float* __restrict__ b1,
    const __bf16* __restrict__ W2z, const float* __restrict__ b2,
    __bf16* __restrict__ Y)
{
  __shared__ __bf16 sH[16*LDT];
  const int lane=threadIdx.x, l15=lane&15, quad=lane>>4;
  const long row0=(long)blockIdx.x*16;
  const long rA=row0+l15;

  bf16x8 fa[4];
  #pragma unroll
  for (int kc=0;kc<4;kc++){
    int kb=kc*32+quad*8;
    float4 u0 = *(const float4*)(X + rA*DIM + kb);
    float4 u1 = *(const float4*)(X + rA*DIM + kb + 4);
    bf16x8 a;
    a[0]=(__bf16)u0.x;a[1]=(__bf16)u0.y;a[2]=(__bf16)u0.z;a[3]=(__bf16)u0.w;
    a[4]=(__bf16)u1.x;a[5]=(__bf16)u1.y;a[6]=(__bf16)u1.z;a[7]=(__bf16)u1.w;
    fa[kc]=a;
  }

  f32x4 acc[8];
  #pragma unroll
  for (int ni=0;ni<8;++ni) acc[ni]=(f32x4){0.f,0.f,0.f,0.f};
  #pragma unroll
  for (int kc=0;kc<4;kc++){
    #pragma unroll
    for (int ni=0;ni<8;ni++){
      bf16x8 w = *(const bf16x8*)(W1z + (long)(kc*512 + ni*64 + lane)*8);
      acc[ni]=mfma16(w,fa[kc],acc[ni]);
    }
  }
  #pragma unroll
  for (int ni=0;ni<8;++ni){
    int n0 = ni*16 + quad*4;
    float4 bb = *(const float4*)(b1 + n0);
    bf16x4 h;
    h[0]=(__bf16)silu_f(acc[ni][0]+bb.x);
    h[1]=(__bf16)silu_f(acc[ni][1]+bb.y);
    h[2]=(__bf16)silu_f(acc[ni][2]+bb.z);
    h[3]=(__bf16)silu_f(acc[ni][3]+bb.w);
    *(bf16x4*)&sH[l15*LDT + n0] = h;
  }
  #pragma unroll
  for (int ni=0;ni<8;++ni) acc[ni]=(f32x4){0.f,0.f,0.f,0.f};
  #pragma unroll
  for (int kc=0;kc<4;kc++){
    bf16x8 h0=*(bf16x8*)&sH[l15*LDT + kc*32 + quad*8];
    #pragma unroll
    for (int ni=0;ni<8;ni++){
      bf16x8 w = *(const bf16x8*)(W2z + (long)(kc*512 + ni*64 + lane)*8);
      acc[ni]=mfma16(w,h0,acc[ni]);
    }
  }
  #pragma unroll
  for (int ni=0;ni<8;++ni){
    int n0 = ni*16 + quad*4;
    float4 bb = *(const float4*)(b2 + n0);
    bf16x4 o;
    o[0]=(__bf16)(acc[ni][0]+bb.x);
    o[1]=(__bf16)(acc[ni][1]+bb.y);
    o[2]=(__bf16)(acc[ni][2]+bb.z);
    o[3]=(__bf16)(acc[ni][3]+bb.w);
    *(bf16x4*)(Y + rA*DIM + n0) = o;
  }
}

// ===========================================================================
// Fused node_update (+) next-layer a-MLP. 1-wave blocks, 16 rows -> 625.
// update (coalesced float4 streams, nx in regs) -> sH (bf16) -> a-GEMM.
// layer==2: write out only (di/xi/phi stores dead).
// ===========================================================================
__global__ __launch_bounds__(64,4) void node_upd_a(
    const float* __restrict__ Rv, const float* __restrict__ uv,
    const float* __restrict__ fi, float* __restrict__ di,
    float* __restrict__ xi, float* __restrict__ phi,
    float* __restrict__ out,
    const __bf16* __restrict__ W1z, const float* __restrict__ b1,
    const __bf16* __restrict__ W2z, const float* __restrict__ b2,
    __bf16* __restrict__ ai, int layer)
{
  __shared__ __bf16 sH[16*LDT];
  const int lane=threadIdx.x, l15=lane&15, quad=lane>>4;
  const long base=(long)blockIdx.x*2048;      // 16 rows * 128 cols

  for (int j=0;j<8;++j){
    const long idx = base + j*256 + lane*4;   // coalesced float4 per lane
    float4 f0 = *(const float4*)(fi + idx);
    float4 f1 = *(const float4*)(fi + NFE + idx);
    float4 f2 = *(const float4*)(fi + 2L*NFE + idx);
    float4 Rq = *(const float4*)(Rv + idx);
    float4 uq = *(const float4*)(uv + idx);
    float4 xq = *(const float4*)(xi + idx);
    float4 ph=(float4){0,0,0,0}, e0=ph, e1=ph, e2=ph;
    if (layer > 0){
      ph = *(const float4*)(phi + idx);
      e0 = *(const float4*)(di + idx);
      e1 = *(const float4*)(di + NFE + idx);
      e2 = *(const float4*)(di + 2L*NFE + idx);
    }
    float4 nd0, nd1, nd2, nx;
    #pragma unroll
    for (int c=0;c<4;++c){
      float d0v = ((const float*)&ph)[c]*((const float*)&e0)[c]
                + ((const float*)&Rq)[c]*((const float*)&f0)[c];
      float d1v = ((const float*)&ph)[c]*((const float*)&e1)[c]
                + ((const float*)&Rq)[c]*((const float*)&f1)[c];
      float d2v = ((const float*)&ph)[c]*((const float*)&e2)[c]
                + ((const float*)&Rq)[c]*((const float*)&f2)[c];
      float sc = ((const float*)&f0)[c]*d0v + ((const float*)&f1)[c]*d1v
               + ((const float*)&f2)[c]*d2v;
      ((float*)&nd0)[c]=d0v; ((float*)&nd1)[c]=d1v; ((float*)&nd2)[c]=d2v;
      ((float*)&nx)[c] = ((const float*)&xq)[c] - ((const float*)&uq)[c]*sc;
    }
    if (layer == 2){
      *(float4*)(out + idx) = nx;           // final output; rest dead
    } else {
      *(float4*)(di + idx)          = nd0;
      *(float4*)(di + NFE + idx)    = nd1;
      *(float4*)(di + 2L*NFE + idx) = nd2;
      *(float4*)(xi + idx) = nx;
      if (layer > 0) *(float4*)(phi + idx) = (float4){0,0,0,0};
      int row = j*2 + (lane>>5);
      int col = (lane*4) & 127;
      bf16x4 h;
      h[0]=(__bf16)nx.x; h[1]=(__bf16)nx.y;
      h[2]=(__bf16)nx.z; h[3]=(__bf16)nx.w;
      *(bf16x4*)&sH[row*LDT + col] = h;     // same-wave, no barrier needed
    }
  }

  if (layer < 2){
    // a-MLP for layer+1 on nx (fragments from sH; single wave)
    bf16x8 fa[4];
    #pragma unroll
    for (int kc=0;kc<4;kc++)
      fa[kc] = *(bf16x8*)&sH[l15*LDT + kc*32 + quad*8];

    f32x4 acc[8];
    #pragma unroll
    for (int ni=0;ni<8;++ni) acc[ni]=(f32x4){0.f,0.f,0.f,0.f};
    #pragma unroll
    for (int kc=0;kc<4;kc++){
      #pragma unroll
      for (int ni=0;ni<8;ni++){
        bf16x8 w = *(const bf16x8*)(W1z + (long)(kc*512 + ni*64 + lane)*8);
        acc[ni]=mfma16(w,fa[kc],acc[ni]);
      }
    }
    #pragma unroll
    for (int ni=0;ni<8;++ni){
      int n0 = ni*16 + quad*4;
      float4 bb = *(const float4*)(b1 + n0);
      bf16x4 h;
      h[0]=(__bf16)silu_f(acc[ni][0]+bb.x);
      h[1]=(__bf16)silu_f(acc[ni][1]+bb.y);
      h[2]=(__bf16)silu_f(acc[ni][2]+bb.z);
      h[3]=(__bf16)silu_f(acc[ni][3]+bb.w);
      *(bf16x4*)&sH[l15*LDT + n0] = h;
    }
    #pragma unroll
    for (int ni=0;ni<8;++ni) acc[ni]=(f32x4){0.f,0.f,0.f,0.f};
    #pragma unroll
    for (int kc=0;kc<4;kc++){
      bf16x8 h0=*(bf16x8*)&sH[l15*LDT + kc*32 + quad*8];
      #pragma unroll
      for (int ni=0;ni<8;ni++){
        bf16x8 w = *(const bf16x8*)(W2z + (long)(kc*512 + ni*64 + lane)*8);
        acc[ni]=mfma16(w,h0,acc[ni]);
      }
    }
    const long rA = (long)blockIdx.x*16 + l15;
    #pragma unroll
    for (int ni=0;ni<8;++ni){
      int n0 = ni*16 + quad*4;
      float4 bb = *(const float4*)(b2 + n0);
      bf16x4 o;
      o[0]=(__bf16)(acc[ni][0]+bb.x);
      o[1]=(__bf16)(acc[ni][1]+bb.y);
      o[2]=(__bf16)(acc[ni][2]+bb.z);
      o[3]=(__bf16)(acc[ni][3]+bb.w);
      *(bf16x4*)(ai + rA*DIM + n0) = o;
    }
  }
}

// ===========================================================================
// One-shot setup: weight swizzle + node init + edge geometry
// ===========================================================================
__global__ __launch_bounds__(256) void setup_all(
    WPtrs wp, __bf16* __restrict__ wt,
    const int* __restrict__ species, const float* __restrict__ spW,
    const float* __restrict__ spB, float* __restrict__ xi, float* __restrict__ fi,
    float* __restrict__ phi,
    const float* __restrict__ dist, const float* __restrict__ vec,
    const float* __restrict__ swv, float* __restrict__ dir, float* __restrict__ rb)
{
  const int b = blockIdx.x, tid = threadIdx.x;
  if (b < 33){
    int t = b/3, l = b%3;
    const float* src = wp.p[t] + (size_t)l*16384;
    __bf16* out = wt + (size_t)b*16384;
    for (int it=0; it<8; ++it){
      int fi_ = it*256 + tid;
      int kc = fi_>>9, ni = (fi_>>6)&7, lane = fi_&63;
      int n  = ni*16 + (lane&15);
      int k0 = kc*32 + (lane>>4)*8;
      bf16x8 v;
      #pragma unroll
      for (int j=0;j<8;++j) v[j] = (__bf16)src[(k0+j)*DIM + n];
      *(bf16x8*)(out + (size_t)fi_*8) = v;
    }
  } else if (b < 33 + 5000){
    int idx = (b-33)*256 + tid;     // < N*128
    int n = idx >> 7, d = idx & 127;
    xi[idx] = spW[species[n]*DIM + d] + spB[d];
    phi[idx] = 0.f;
    fi[idx] = 0.f;                  // plane 0
    fi[NFE + idx] = 0.f;            // plane 1
    fi[2L*NFE + idx] = 0.f;         // plane 2
  } else {
    int e = (b-5033)*256 + tid;
    if (e < N_EDGES){
      float d = dist[e];
      float s = swv[e];
      float inv = s / d;
      dir[e*3+0] = vec[e*3+0]*inv;
      dir[e*3+1] = vec[e*3+1]*inv;
      dir[e*3+2] = vec[e*3+2]*inv;
      const float eta = (16.0f/5.0f)*(16.0f/5.0f);
      #pragma unroll
      for (int j=0;j<NBASIS;j++){
        float c = (float)j * (5.0f/15.0f);
        float t2 = d - c;
        rb[e*NBASIS + j] = __expf(-eta*t2*t2);
      }
    }
  }
}

// mij = ai[src]*ai[dst]*(rb@radW + radB)*sw  AND  xi += segsum(mij).
// 64 edges/block, wave wv owns edges [16wv,16wv+16). radW cols in regs.
__global__ __launch_bounds__(256) void mij_segsum(
    const __bf16* __restrict__ ai, const int* __restrict__ esrc, const int* __restrict__ edst,
    const float* __restrict__ swv, const float* __restrict__ rb,
    const float* __restrict__ radW, const float* __restrict__ radB,
    __bf16* __restrict__ mij, float* __restrict__ xi)
{
  __shared__ float sRb[64*NBASIS];
  __shared__ int   sS[64], sD[64];
  __shared__ float sSw[64];
  int tid = threadIdx.x;
  int e0 = blockIdx.x * 64;
  *(float4*)(sRb + tid*4) = *(const float4*)(rb + (long)e0*NBASIS + tid*4);
  if (tid < 64){
    sS[tid]  = esrc[e0+tid];
    sD[tid]  = edst[e0+tid];
    sSw[tid] = swv[e0+tid];
  }
  const int wv = tid>>6, lane = tid&63;
  const int d = lane*2;
  float2 rw[NBASIS];
  #pragma unroll
  for (int j=0;j<NBASIS;j++)
    rw[j] = *(const float2*)(radW + j*DIM + d);
  float2 rB = *(const float2*)(radB + d);
  __syncthreads();

  float sx=0.f, sy=0.f;
  int cur = sS[wv*16];
  #pragma unroll
  for (int i=0;i<16;i++){
    int el = wv*16 + i;
    int n = sS[el];
    if (n != cur){                       // wave-uniform branch
      atomicAdd(&xi[(long)cur*DIM+d  ], sx);
      atomicAdd(&xi[(long)cur*DIM+d+1], sy);
      sx=0.f; sy=0.f; cur=n;
    }
    bf16x2 as = *(const bf16x2*)(ai + (long)n*DIM + d);
    bf16x2 ad = *(const bf16x2*)(ai + (long)sD[el]*DIM + d);
    float acc0 = 0.f, acc1 = 0.f;
    #pragma unroll
    for (int j=0;j<NBASIS;j++){
      float rbv = sRb[el*NBASIS+j];
      acc0 += rbv*rw[j].x;
      acc1 += rbv*rw[j].y;
    }
    float sw_ = sSw[el];
    float m0 = (float)as[0]*(float)ad[0]*(acc0+rB.x)*sw_;
    float m1 = (float)as[1]*(float)ad[1]*(acc1+rB.y)*sw_;
    bf16x2 m; m[0]=(__bf16)m0; m[1]=(__bf16)m1;
    *(bf16x2*)(mij + (long)(e0+el)*DIM + d) = m;
    sx += m0; sy += m1;
  }
  atomicAdd(&xi[(long)cur*DIM+d  ], sx);
  atomicAdd(&xi[(long)cur*DIM+d+1], sy);
}

extern "C" void kernel_launch(void* const* d_in, const int* in_sizes, int n_in,
                              void* d_out, int out_size, void* d_ws, size_t ws_size,
                              hipStream_t stream) {
  const int*   species = (const int*)  d_in[0];
  const int*   esrc    = (const int*)  d_in[1];
  const int*   edst    = (const int*)  d_in[2];
  const float* dist    = (const float*)d_in[3];
  const float* vec     = (const float*)d_in[4];
  const float* swv     = (const float*)d_in[5];
  const float* spW     = (const float*)d_in[6];
  const float* spB     = (const float*)d_in[7];
  const float* radW    = (const float*)d_in[8];
  const float* radB    = (const float*)d_in[9];
  const float* aW1=(const float*)d_in[10], *aB1=(const float*)d_in[11], *aW2=(const float*)d_in[12], *aB2=(const float*)d_in[13];
  const float* FW1=(const float*)d_in[14], *FB1=(const float*)d_in[15], *FW2=(const float*)d_in[16], *FB2=(const float*)d_in[17];
  const float* fW1=(const float*)d_in[18], *fB1=(const float*)d_in[19], *fW2=(const float*)d_in[20], *fB2=(const float*)d_in[21];
  const float* RW1=(const float*)d_in[22], *RB1=(const float*)d_in[23], *RW2=(const float*)d_in[24], *RB2=(const float*)d_in[25];
  const float* rW1=(const float*)d_in[26], *rB1=(const float*)d_in[27], *rW2=(const float*)d_in[28], *rB2=(const float*)d_in[29];
  const float* uW1=(const float*)d_in[30], *uB1=(const float*)d_in[31], *uW2=(const float*)d_in[32], *uB2=(const float*)d_in[33];

  const long NF = (long)N_NODES*DIM;      // 1,280,000
  const long EF = (long)N_EDGES*DIM;      // 20,480,000
  float* ws   = (float*)d_ws;
  float* xi   = ws;
  float* Rv   = xi   + NF;
  float* uv   = Rv   + NF;
  float* phi  = uv   + NF;
  float* fi   = phi  + NF;                // 3 planes of NF
  float* di   = fi   + 3*NF;              // 3 planes of NF
  float* dir  = di   + 3*NF;
  float* rb   = dir  + 3L*N_EDGES;
  char* bp = (char*)(rb + 16L*N_EDGES);
  size_t off = ((size_t)(bp - (char*)d_ws) + 15) & ~(size_t)15;
  __bf16* ai   = (__bf16*)((char*)d_ws + off);
  __bf16* mij  = ai  + NF;
  __bf16* wt   = mij + EF;                // 33 x 128x128 bf16 (swizzled)

  // swizzled bf16 weights: tensor order a1,a2,F1,f1,f2,R1,R2,r1,r2,u1,u2
  WPtrs wp;
  wp.p[0]=aW1; wp.p[1]=aW2; wp.p[2]=FW1; wp.p[3]=fW1; wp.p[4]=fW2;
  wp.p[5]=RW1; wp.p[6]=RW2; wp.p[7]=rW1; wp.p[8]=rW2; wp.p[9]=uW1; wp.p[10]=uW2;

  // one-shot setup: 33 convert + 5000 init + 625 geom = 5658 blocks
  setup_all<<<5658, 256, 0, stream>>>(wp, wt,
                                      species, spW, spB, xi, fi, phi,
                                      dist, vec, swv, dir, rb);

  const int nodeB = (N_NODES + 63)/64;        // 157 (node part of mlp_layer)
  const int edgeB = N_EDGES/128;              // 1250
  #define WT(t,l) (wt + (size_t)((t)*3+(l))*16384)

  // a-MLP for layer 0 (layers 1,2 produced by node_upd_a)
  mlp_a<<<N_NODES/16, 64, 0, stream>>>(xi, WT(0,0), aB1, WT(1,0), aB2, ai);

  for (int l=0;l<3;l++){
    const long bo = (long)l*DIM;

    // mij (bf16) + xi += segsum(mij)   [fused, atomics]
    mij_segsum<<<N_EDGES/64, 256, 0, stream>>>(ai, esrc, edst, swv, rb,
                                               radW + (long)l*NBASIS*DIM, radB + bo,
                                               mij, xi);
    // combined: [node] Rv,uv  +  [edge] f/F[/r] MLPs with wave-local
    // fi/phi segment reductions (no ef/ephi in HBM; plane-coalesced atomics)
    if (l == 0)
      mlp_layer<false><<<nodeB+edgeB, 256, 0, stream>>>(
          nodeB, mij, esrc, dir,
          WT(3,l), fB1+bo, WT(4,l), fB2+bo,
          WT(2,l), FB1+bo, FW2+(long)l*DIM, FB2+l,
          nullptr, nullptr, nullptr, nullptr, nullptr,
          fi, phi,
          xi, WT(5,l), RB1+bo, WT(6,l), RB2+bo,
          WT(9,l), uB1+bo, WT(10,l), uB2+bo, Rv, uv);
    else
      mlp_layer<true><<<nodeB+edgeB, 256, 0, stream>>>(
          nodeB, mij, esrc, dir,
          WT(3,l), fB1+bo, WT(4,l), fB2+bo,
          WT(2,l), FB1+bo, FW2+(long)l*DIM, FB2+l,
          WT(7,l), rB1+bo, WT(8,l), rB2+bo, swv,
          fi, phi,
          xi, WT(5,l), RB1+bo, WT(6,l), RB2+bo,
          WT(9,l), uB1+bo, WT(10,l), uB2+bo, Rv, uv);
    // fused: di/scal/xi update + a-MLP(l+1); zeroes phi; out on l==2
    int ln = (l < 2) ? (l+1) : 0;
    node_upd_a<<<N_NODES/16, 64, 0, stream>>>(
        Rv, uv, fi, di, xi, phi, (float*)d_out,
        WT(0,ln), aB1+(long)ln*DIM, WT(1,ln), aB2+(long)ln*DIM, ai, l);
  }
}

// Round 6
// 486.351 us; speedup vs baseline: 1.2600x; 1.0083x over previous
//
#include <hip/hip_runtime.h>
#include <hip/hip_bf16.h>

#define N_NODES 10000
#define N_EDGES 160000
#define DIM     128
#define NBASIS  16
#define LDT     136   // LDS row stride (bf16); 272B row, 16B aligned
#define NFE     (N_NODES*DIM)   // 1,280,000 elements per plane

typedef __bf16 bf16x8 __attribute__((ext_vector_type(8)));
typedef __bf16 bf16x4 __attribute__((ext_vector_type(4)));
typedef __bf16 bf16x2 __attribute__((ext_vector_type(2)));
typedef float  f32x4  __attribute__((ext_vector_type(4)));

__device__ __forceinline__ float silu_f(float x){
  return x * (1.0f / (1.0f + __expf(-x)));
}
__device__ __forceinline__ f32x4 mfma16(bf16x8 a, bf16x8 b, f32x4 c){
  return __builtin_amdgcn_mfma_f32_16x16x32_bf16(a,b,c,0,0,0);
}

// Swizzled weight layout: frag (kc,ni,lane) at Wz[(kc*512+ni*64+lane)*8+j].
// Design log: r9 LDS weights; r10 operand-swap; r11 fused mij+segsum;
// r12 reg radW; r13 node-MLP merge; r16/r17 in-kernel fi/phi reduction;
// r18 ping-pong sW reg-staging (1 barrier/phase) -> 504us (mlp_layer 90us).
// r19 FAILED (694): (256,4) on unified VGPR/AGPR file -> 64V, spills.
// r20 FAILED (641): direct-global weights latency-serialize.
// r21 FAILED (531): global_load_lds staging; vmcnt(0) drain at barriers.
// r22 FAILED (613): mij-fusion serializes block head; 157-blk node kernel
// loses r13 overlap. Occupancy is DOUBLE-capped: 128V+64A=192 unified regs
// (2 waves/SIMD) AND 70KB LDS (2 blk/CU).
// r23 WIN (490): node_update(+)mlp_a fusion -> node_upd_a. BUT sDir staging
// via 3 stride-3 scalar loads cost +4.4us/dispatch vs r18's coalesced f4.
// r24: (a) sDir hybrid -- coalesced float4 load (96 thr) + 4x ds_write_b32
// scatter into stride-4 layout: r18's fast load + r23's b128 read;
// (b) mij_segsum: hoist all 32 ai gathers ahead of the accumulate loop
// (2x8-edge reg groups, +32 VGPR, still <=128 band, bound (256,4)).
// r8 lesson: smaller edge tiles double chip-wide weight traffic.
// r6 lesson (re-learned r19): never force min-waves below live state.

struct WPtrs { const float* p[11]; };

// ===========================================================================
// Combined per-layer MLP dispatch.
//  blocks [0, nodeB):   R- and u-MLPs on xi (64 rows/block, 4 indep waves)
//  blocks [nodeB, ...): edge MLPs on mij (128 edges/block) + wave-local
//                       segment reduction of ef*dir -> fi planes, ephi -> phi.
// ===========================================================================
template<bool WITH_R>
__global__ __launch_bounds__(256,2) void mlp_layer(
    int nodeB,
    const __bf16* __restrict__ mij,
    const int*    __restrict__ esrc, const float* __restrict__ dirv,
    const __bf16* __restrict__ fW1z, const float* __restrict__ fb1,
    const __bf16* __restrict__ fW2z, const float* __restrict__ fb2,
    const __bf16* __restrict__ FW1z, const float* __restrict__ Fb1,
    const float*  __restrict__ FW2v, const float* __restrict__ Fb2,
    const __bf16* __restrict__ rW1z, const float* __restrict__ rb1,
    const __bf16* __restrict__ rW2z, const float* __restrict__ rb2,
    const float*  __restrict__ swv,
    float* __restrict__ fiG, float* __restrict__ phiG,
    const float* __restrict__ X,
    const __bf16* __restrict__ RW1z, const float* __restrict__ Rb1,
    const __bf16* __restrict__ RW2z, const float* __restrict__ Rb2,
    const __bf16* __restrict__ uW1z, const float* __restrict__ ub1,
    const __bf16* __restrict__ uW2z, const float* __restrict__ ub2,
    float* __restrict__ Rv, float* __restrict__ uv)
{
  __shared__ __bf16 sH[128*LDT];   // 34816 B
  __shared__ __bf16 sW[2][8192];   // 32768 B (ping-pong)
  __shared__ int    sE[128];       //   512 B
  __shared__ float  sDir[128*4];   //  2048 B  (total 70144 -> 2 blocks/CU)
  const int tid=threadIdx.x, lane=tid&63, wv=tid>>6, l15=lane&15, quad=lane>>4;

  if ((int)blockIdx.x < nodeB){
    // ---------------- node path: R and u MLPs, 16 rows per wave -----------
    const long row0n = (long)blockIdx.x*64 + wv*16;
    const long rA = row0n + l15;
    const bool okA = rA < N_NODES;

    bf16x8 fa[4];
    #pragma unroll
    for (int kc=0;kc<4;kc++){
      int kb=kc*32+quad*8;
      bf16x8 a;
      #pragma unroll
      for (int i=0;i<8;i++) a[i]=(__bf16)0.f;
      if (okA){
        float4 u0 = *(const float4*)(X + rA*DIM + kb);
        float4 u1 = *(const float4*)(X + rA*DIM + kb + 4);
        a[0]=(__bf16)u0.x;a[1]=(__bf16)u0.y;a[2]=(__bf16)u0.z;a[3]=(__bf16)u0.w;
        a[4]=(__bf16)u1.x;a[5]=(__bf16)u1.y;a[6]=(__bf16)u1.z;a[7]=(__bf16)u1.w;
      }
      fa[kc]=a;
    }

    f32x4 acc[8];
    auto zacc = [&](){
      #pragma unroll
      for (int ni=0;ni<8;++ni) acc[ni]=(f32x4){0.f,0.f,0.f,0.f};
    };
    auto gemmA = [&](const __bf16* __restrict__ Wz){
      #pragma unroll
      for (int kc=0;kc<4;kc++){
        #pragma unroll
        for (int ni=0;ni<8;ni++){
          bf16x8 w = *(const bf16x8*)(Wz + (long)(kc*512 + ni*64 + lane)*8);
          acc[ni]=mfma16(w,fa[kc],acc[ni]);
        }
      }
    };
    auto gemmH = [&](const __bf16* __restrict__ Wz){
      #pragma unroll
      for (int kc=0;kc<4;kc++){
        bf16x8 h0=*(bf16x8*)&sH[(wv*16+l15)*LDT + kc*32 + quad*8];
        #pragma unroll
        for (int ni=0;ni<8;ni++){
          bf16x8 w = *(const bf16x8*)(Wz + (long)(kc*512 + ni*64 + lane)*8);
          acc[ni]=mfma16(w,h0,acc[ni]);
        }
      }
    };
    auto hEpi = [&](const float* __restrict__ b1){
      #pragma unroll
      for (int ni=0;ni<8;++ni){
        int n0 = ni*16 + quad*4;
        float4 bb = *(const float4*)(b1 + n0);
        bf16x4 h;
        h[0]=(__bf16)silu_f(acc[ni][0]+bb.x);
        h[1]=(__bf16)silu_f(acc[ni][1]+bb.y);
        h[2]=(__bf16)silu_f(acc[ni][2]+bb.z);
        h[3]=(__bf16)silu_f(acc[ni][3]+bb.w);
        *(bf16x4*)&sH[(wv*16+l15)*LDT + n0] = h;
      }
    };
    auto cStoreF = [&](const float* __restrict__ b2, float* __restrict__ Y){
      if (okA){
        #pragma unroll
        for (int ni=0;ni<8;++ni){
          int n0 = ni*16 + quad*4;
          float4 bb = *(const float4*)(b2 + n0);
          float4 o;
          o.x=acc[ni][0]+bb.x; o.y=acc[ni][1]+bb.y;
          o.z=acc[ni][2]+bb.z; o.w=acc[ni][3]+bb.w;
          *(float4*)(Y + rA*DIM + n0) = o;
        }
      }
    };

    zacc(); gemmA(RW1z); hEpi(Rb1);
    zacc(); gemmH(RW2z); cStoreF(Rb2, Rv);
    zacc(); gemmA(uW1z); hEpi(ub1);
    zacc(); gemmH(uW2z); cStoreF(ub2, uv);
    return;
  }

  // ---------------- edge path: F/f[/r] MLPs on mij ------------------------
  const long row0 = (long)(blockIdx.x - nodeB)*128;
  const int  rloc0 = wv*32 + l15;
  const long rB0 = row0 + rloc0, rB1 = rB0+16;

  // stage esrc + dir for this block's 128 edges.
  // dir: coalesced float4 loads (96 threads) scattered into stride-4 LDS
  // (f = t*4+j -> edge f/3, comp f%3); published by first barrier.
  if (tid < 32)  *(int4*)&sE[tid*4] = *(const int4*)(esrc + row0 + tid*4);
  if (tid >= 64 && tid < 160){
    int t = tid - 64;                  // 0..95
    float4 v = *(const float4*)(dirv + row0*3 + t*4);
    #pragma unroll
    for (int j=0;j<4;++j){
      int f = t*4 + j;                 // 0..383
      sDir[(f/3)*4 + (f%3)] = ((const float*)&v)[j];
    }
  }

  bf16x8 fb[2][4];
  #pragma unroll
  for (int kc=0;kc<4;kc++){
    fb[0][kc] = *(const bf16x8*)(mij + rB0*DIM + kc*32 + quad*8);
    fb[1][kc] = *(const bf16x8*)(mij + rB1*DIM + kc*32 + quad*8);
  }
  float swr[2];
  if constexpr (WITH_R){ swr[0]=swv[rB0]; swr[1]=swv[rB1]; }

  f32x4 acc[2][8];
  bf16x8 pre[4];
  float eF[2];

  auto preload = [&](const __bf16* __restrict__ Wz, int half){
    #pragma unroll
    for (int it=0; it<4; ++it)
      pre[it] = *(const bf16x8*)(Wz + (long)(half*1024 + it*256 + tid)*8);
  };
  auto writePre = [&](int b){
    #pragma unroll
    for (int it=0; it<4; ++it)
      *(bf16x8*)&sW[b][(it*256+tid)*8] = pre[it];
  };
  auto zacc = [&](){
    #pragma unroll
    for (int mi=0;mi<2;++mi)
      #pragma unroll
      for (int ni=0;ni<8;++ni) acc[mi][ni]=(f32x4){0.f,0.f,0.f,0.f};
  };
  auto mfmaB = [&](int b, int half){
    #pragma unroll
    for (int k2=0;k2<2;k2++){
      int kc = half*2 + k2;
      #pragma unroll
      for (int ni=0;ni<8;ni++){
        bf16x8 w = *(bf16x8*)&sW[b][(k2*512 + ni*64 + lane)*8];
        acc[0][ni]=mfma16(w,fb[0][kc],acc[0][ni]);
        acc[1][ni]=mfma16(w,fb[1][kc],acc[1][ni]);
      }
    }
  };
  auto mfmaH = [&](int b, int half){
    #pragma unroll
    for (int k2=0;k2<2;k2++){
      int kc = half*2 + k2;
      bf16x8 h0=*(bf16x8*)&sH[(rloc0   )*LDT + kc*32 + quad*8];
      bf16x8 h1=*(bf16x8*)&sH[(rloc0+16)*LDT + kc*32 + quad*8];
      #pragma unroll
      for (int ni=0;ni<8;ni++){
        bf16x8 w = *(bf16x8*)&sW[b][(k2*512 + ni*64 + lane)*8];
        acc[0][ni]=mfma16(w,h0,acc[0][ni]);
        acc[1][ni]=mfma16(w,h1,acc[1][ni]);
      }
    }
  };
  auto fEpi = [&](){
    float fb2v = Fb2[0];
    #pragma unroll
    for (int mi=0;mi<2;++mi){
      float p = 0.f;
      #pragma unroll
      for (int ni=0;ni<8;++ni){
        int n0 = ni*16 + quad*4;
        float4 bb = *(const float4*)(Fb1 + n0);
        float4 w2 = *(const float4*)(FW2v + n0);
        p += silu_f(acc[mi][ni][0]+bb.x)*w2.x;
        p += silu_f(acc[mi][ni][1]+bb.y)*w2.y;
        p += silu_f(acc[mi][ni][2]+bb.z)*w2.z;
        p += silu_f(acc[mi][ni][3]+bb.w)*w2.w;
      }
      p += __shfl_xor(p,16);
      p += __shfl_xor(p,32);
      eF[mi] = p + fb2v;
    }
  };
  auto hEpi = [&](const float* __restrict__ b1){
    #pragma unroll
    for (int mi=0;mi<2;++mi){
      int rl = wv*32 + mi*16 + l15;
      #pragma unroll
      for (int ni=0;ni<8;++ni){
        int n0 = ni*16 + quad*4;
        float4 bb = *(const float4*)(b1 + n0);
        bf16x4 h;
        h[0]=(__bf16)silu_f(acc[mi][ni][0]+bb.x);
        h[1]=(__bf16)silu_f(acc[mi][ni][1]+bb.y);
        h[2]=(__bf16)silu_f(acc[mi][ni][2]+bb.z);
        h[3]=(__bf16)silu_f(acc[mi][ni][3]+bb.w);
        *(bf16x4*)&sH[rl*LDT + n0] = h;
      }
    }
  };
  // MLP output (x bias x mul) -> sH (wave-private rows), bf16
  auto outLDS = [&](const float* __restrict__ b2, const float* mul){
    #pragma unroll
    for (int mi=0;mi<2;++mi){
      int rl = wv*32 + mi*16 + l15;
      #pragma unroll
      for (int ni=0;ni<8;++ni){
        int n0 = ni*16 + quad*4;
        float4 bb = *(const float4*)(b2 + n0);
        bf16x4 o;
        o[0]=(__bf16)((acc[mi][ni][0]+bb.x)*mul[mi]);
        o[1]=(__bf16)((acc[mi][ni][1]+bb.y)*mul[mi]);
        o[2]=(__bf16)((acc[mi][ni][2]+bb.z)*mul[mi]);
        o[3]=(__bf16)((acc[mi][ni][3]+bb.w)*mul[mi]);
        *(bf16x4*)&sH[rl*LDT + n0] = o;
      }
    }
  };
  // wave wv reduces its OWN edges [32wv,32wv+32) over all 128 cols.
  // Same-wave LDS write->read ordering (lgkmcnt) -- no barrier needed.
  auto reduceFi = [&](){
    const int d = lane*2;
    float a0=0.f,a1=0.f,a2=0.f,a3=0.f,a4=0.f,a5=0.f;
    int cur = sE[wv*32];
    for (int i=0;i<32;i++){
      int e = wv*32+i;
      int n = sE[e];
      if (n != cur){                    // wave-uniform
        long b = (long)cur*DIM + d;
        atomicAdd(&fiG[0L*NFE + b  ], a0);
        atomicAdd(&fiG[0L*NFE + b+1], a3);
        atomicAdd(&fiG[1L*NFE + b  ], a1);
        atomicAdd(&fiG[1L*NFE + b+1], a4);
        atomicAdd(&fiG[2L*NFE + b  ], a2);
        atomicAdd(&fiG[2L*NFE + b+1], a5);
        a0=a1=a2=a3=a4=a5=0.f; cur=n;
      }
      bf16x2 v = *(bf16x2*)&sH[e*LDT + d];
      float vx=(float)v[0], vy=(float)v[1];
      float4 dv = *(float4*)&sDir[e*4];  // broadcast b128
      a0+=vx*dv.x; a1+=vx*dv.y; a2+=vx*dv.z;
      a3+=vy*dv.x; a4+=vy*dv.y; a5+=vy*dv.z;
    }
    long b = (long)cur*DIM + d;
    atomicAdd(&fiG[0L*NFE + b  ], a0);
    atomicAdd(&fiG[0L*NFE + b+1], a3);
    atomicAdd(&fiG[1L*NFE + b  ], a1);
    atomicAdd(&fiG[1L*NFE + b+1], a4);
    atomicAdd(&fiG[2L*NFE + b  ], a2);
    atomicAdd(&fiG[2L*NFE + b+1], a5);
  };
  auto reducePhi = [&](){
    const int d = lane*2;
    float a0=0.f,a1=0.f;
    int cur = sE[wv*32];
    for (int i=0;i<32;i++){
      int e = wv*32+i;
      int n = sE[e];
      if (n != cur){
        atomicAdd(&phiG[(long)cur*DIM + d  ], a0);
        atomicAdd(&phiG[(long)cur*DIM + d+1], a1);
        a0=a1=0.f; cur=n;
      }
      bf16x2 v = *(bf16x2*)&sH[e*LDT + d];
      a0 += (float)v[0]; a1 += (float)v[1];
    }
    atomicAdd(&phiG[(long)cur*DIM + d  ], a0);
    atomicAdd(&phiG[(long)cur*DIM + d+1], a1);
  };

  // ------- ping-pong pipeline: 1 barrier per phase (publish next buf) ------
  preload(FW1z,0); writePre(0);
  __syncthreads();                  // B0 + sE/sDir published
  preload(FW1z,1);
  zacc(); mfmaB(0,0);
  writePre(1);
  __syncthreads();                  // B1 published
  preload(fW1z,0);
  mfmaB(1,1);
  writePre(0);
  __syncthreads();
  preload(fW1z,1);
  fEpi();
  zacc(); mfmaB(0,0);
  writePre(1);
  __syncthreads();
  preload(fW2z,0);
  mfmaB(1,1);
  writePre(0);
  __syncthreads();
  preload(fW2z,1);
  hEpi(fb1);
  zacc(); mfmaH(0,0);
  writePre(1);
  __syncthreads();
  if constexpr (WITH_R) preload(rW1z,0);
  mfmaH(1,1);
  outLDS(fb2, eF);                  // ef -> own sH rows
  reduceFi();                       // wave-local: fi += ef*dir

  if constexpr (WITH_R){
    writePre(0);
    __syncthreads();
    preload(rW1z,1);
    zacc(); mfmaB(0,0);
    writePre(1);
    __syncthreads();
    preload(rW2z,0);
    mfmaB(1,1);
    writePre(0);
    __syncthreads();
    preload(rW2z,1);
    hEpi(rb1);
    zacc(); mfmaH(0,0);
    writePre(1);
    __syncthreads();
    mfmaH(1,1);
    outLDS(rb2, swr);               // ephi -> own sH rows
    reducePhi();                    // wave-local: phi += ephi
  }
}

// ===========================================================================
// Node MLP a (layer 0 only): 1-wave blocks, 16 rows each -> 625 blocks.
// ===========================================================================
__global__ __launch_bounds__(64,4) void mlp_a(
    const float* __restrict__ X,
    const __bf16* __restrict__ W1z, const float* __restrict__ b1,
    const __bf16* __restrict__ W2z, const float* __restrict__ b2,
    __bf16* __restrict__ Y)
{
  __shared__ __bf16 sH[16*LDT];
  const int lane=threadIdx.x, l15=lane&15, quad=lane>>4;
  const long row0=(long)blockIdx.x*16;
  const long rA=row0+l15;

  bf16x8 fa[4];
  #pragma unroll
  for (int kc=0;kc<4;kc++){
    int kb=kc*32+quad*8;
    float4 u0 = *(const float4*)(X + rA*DIM + kb);
    float4 u1 = *(const float4*)(X + rA*DIM + kb + 4);
    bf16x8 a;
    a[0]=(__bf16)u0.x;a[1]=(__bf16)u0.y;a[2]=(__bf16)u0.z;a[3]=(__bf16)u0.w;
    a[4]=(__bf16)u1.x;a[5]=(__bf16)u1.y;a[6]=(__bf16)u1.z;a[7]=(__bf16)u1.w;
    fa[kc]=a;
  }

  f32x4 acc[8];
  #pragma unroll
  for (int ni=0;ni<8;++ni) acc[ni]=(f32x4){0.f,0.f,0.f,0.f};
  #pragma unroll
  for (int kc=0;kc<4;kc++){
    #pragma unroll
    for (int ni=0;ni<8;ni++){
      bf16x8 w = *(const bf16x8*)(W1z + (long)(kc*512 + ni*64 + lane)*8);
      acc[ni]=mfma16(w,fa[kc],acc[ni]);
    }
  }
  #pragma unroll
  for (int ni=0;ni<8;++ni){
    int n0 = ni*16 + quad*4;
    float4 bb = *(const float4*)(b1 + n0);
    bf16x4 h;
    h[0]=(__bf16)silu_f(acc[ni][0]+bb.x);
    h[1]=(__bf16)silu_f(acc[ni][1]+bb.y);
    h[2]=(__bf16)silu_f(acc[ni][2]+bb.z);
    h[3]=(__bf16)silu_f(acc[ni][3]+bb.w);
    *(bf16x4*)&sH[l15*LDT + n0] = h;
  }
  #pragma unroll
  for (int ni=0;ni<8;++ni) acc[ni]=(f32x4){0.f,0.f,0.f,0.f};
  #pragma unroll
  for (int kc=0;kc<4;kc++){
    bf16x8 h0=*(bf16x8*)&sH[l15*LDT + kc*32 + quad*8];
    #pragma unroll
    for (int ni=0;ni<8;ni++){
      bf16x8 w = *(const bf16x8*)(W2z + (long)(kc*512 + ni*64 + lane)*8);
      acc[ni]=mfma16(w,h0,acc[ni]);
    }
  }
  #pragma unroll
  for (int ni=0;ni<8;++ni){
    int n0 = ni*16 + quad*4;
    float4 bb = *(const float4*)(b2 + n0);
    bf16x4 o;
    o[0]=(__bf16)(acc[ni][0]+bb.x);
    o[1]=(__bf16)(acc[ni][1]+bb.y);
    o[2]=(__bf16)(acc[ni][2]+bb.z);
    o[3]=(__bf16)(acc[ni][3]+bb.w);
    *(bf16x4*)(Y + rA*DIM + n0) = o;
  }
}

// ===========================================================================
// Fused node_update (+) next-layer a-MLP. 1-wave blocks, 16 rows -> 625.
// update (coalesced float4 streams, nx in regs) -> sH (bf16) -> a-GEMM.
// layer==2: write out only (di/xi/phi stores dead).
// ===========================================================================
__global__ __launch_bounds__(64,4) void node_upd_a(
    const float* __restrict__ Rv, const float* __restrict__ uv,
    const float* __restrict__ fi, float* __restrict__ di,
    float* __restrict__ xi, float* __restrict__ phi,
    float* __restrict__ out,
    const __bf16* __restrict__ W1z, const float* __restrict__ b1,
    const __bf16* __restrict__ W2z, const float* __restrict__ b2,
    __bf16* __restrict__ ai, int layer)
{
  __shared__ __bf16 sH[16*LDT];
  const int lane=threadIdx.x, l15=lane&15, quad=lane>>4;
  const long base=(long)blockIdx.x*2048;      // 16 rows * 128 cols

  for (int j=0;j<8;++j){
    const long idx = base + j*256 + lane*4;   // coalesced float4 per lane
    float4 f0 = *(const float4*)(fi + idx);
    float4 f1 = *(const float4*)(fi + NFE + idx);
    float4 f2 = *(const float4*)(fi + 2L*NFE + idx);
    float4 Rq = *(const float4*)(Rv + idx);
    float4 uq = *(const float4*)(uv + idx);
    float4 xq = *(const float4*)(xi + idx);
    float4 ph=(float4){0,0,0,0}, e0=ph, e1=ph, e2=ph;
    if (layer > 0){
      ph = *(const float4*)(phi + idx);
      e0 = *(const float4*)(di + idx);
      e1 = *(const float4*)(di + NFE + idx);
      e2 = *(const float4*)(di + 2L*NFE + idx);
    }
    float4 nd0, nd1, nd2, nx;
    #pragma unroll
    for (int c=0;c<4;++c){
      float d0v = ((const float*)&ph)[c]*((const float*)&e0)[c]
                + ((const float*)&Rq)[c]*((const float*)&f0)[c];
      float d1v = ((const float*)&ph)[c]*((const float*)&e1)[c]
                + ((const float*)&Rq)[c]*((const float*)&f1)[c];
      float d2v = ((const float*)&ph)[c]*((const float*)&e2)[c]
                + ((const float*)&Rq)[c]*((const float*)&f2)[c];
      float sc = ((const float*)&f0)[c]*d0v + ((const float*)&f1)[c]*d1v
               + ((const float*)&f2)[c]*d2v;
      ((float*)&nd0)[c]=d0v; ((float*)&nd1)[c]=d1v; ((float*)&nd2)[c]=d2v;
      ((float*)&nx)[c] = ((const float*)&xq)[c] - ((const float*)&uq)[c]*sc;
    }
    if (layer == 2){
      *(float4*)(out + idx) = nx;           // final output; rest dead
    } else {
      *(float4*)(di + idx)          = nd0;
      *(float4*)(di + NFE + idx)    = nd1;
      *(float4*)(di + 2L*NFE + idx) = nd2;
      *(float4*)(xi + idx) = nx;
      if (layer > 0) *(float4*)(phi + idx) = (float4){0,0,0,0};
      int row = j*2 + (lane>>5);
      int col = (lane*4) & 127;
      bf16x4 h;
      h[0]=(__bf16)nx.x; h[1]=(__bf16)nx.y;
      h[2]=(__bf16)nx.z; h[3]=(__bf16)nx.w;
      *(bf16x4*)&sH[row*LDT + col] = h;     // same-wave, no barrier needed
    }
  }

  if (layer < 2){
    // a-MLP for layer+1 on nx (fragments from sH; single wave)
    bf16x8 fa[4];
    #pragma unroll
    for (int kc=0;kc<4;kc++)
      fa[kc] = *(bf16x8*)&sH[l15*LDT + kc*32 + quad*8];

    f32x4 acc[8];
    #pragma unroll
    for (int ni=0;ni<8;++ni) acc[ni]=(f32x4){0.f,0.f,0.f,0.f};
    #pragma unroll
    for (int kc=0;kc<4;kc++){
      #pragma unroll
      for (int ni=0;ni<8;ni++){
        bf16x8 w = *(const bf16x8*)(W1z + (long)(kc*512 + ni*64 + lane)*8);
        acc[ni]=mfma16(w,fa[kc],acc[ni]);
      }
    }
    #pragma unroll
    for (int ni=0;ni<8;++ni){
      int n0 = ni*16 + quad*4;
      float4 bb = *(const float4*)(b1 + n0);
      bf16x4 h;
      h[0]=(__bf16)silu_f(acc[ni][0]+bb.x);
      h[1]=(__bf16)silu_f(acc[ni][1]+bb.y);
      h[2]=(__bf16)silu_f(acc[ni][2]+bb.z);
      h[3]=(__bf16)silu_f(acc[ni][3]+bb.w);
      *(bf16x4*)&sH[l15*LDT + n0] = h;
    }
    #pragma unroll
    for (int ni=0;ni<8;++ni) acc[ni]=(f32x4){0.f,0.f,0.f,0.f};
    #pragma unroll
    for (int kc=0;kc<4;kc++){
      bf16x8 h0=*(bf16x8*)&sH[l15*LDT + kc*32 + quad*8];
      #pragma unroll
      for (int ni=0;ni<8;ni++){
        bf16x8 w = *(const bf16x8*)(W2z + (long)(kc*512 + ni*64 + lane)*8);
        acc[ni]=mfma16(w,h0,acc[ni]);
      }
    }
    const long rA = (long)blockIdx.x*16 + l15;
    #pragma unroll
    for (int ni=0;ni<8;++ni){
      int n0 = ni*16 + quad*4;
      float4 bb = *(const float4*)(b2 + n0);
      bf16x4 o;
      o[0]=(__bf16)(acc[ni][0]+bb.x);
      o[1]=(__bf16)(acc[ni][1]+bb.y);
      o[2]=(__bf16)(acc[ni][2]+bb.z);
      o[3]=(__bf16)(acc[ni][3]+bb.w);
      *(bf16x4*)(ai + rA*DIM + n0) = o;
    }
  }
}

// ===========================================================================
// One-shot setup: weight swizzle + node init + edge geometry
// ===========================================================================
__global__ __launch_bounds__(256) void setup_all(
    WPtrs wp, __bf16* __restrict__ wt,
    const int* __restrict__ species, const float* __restrict__ spW,
    const float* __restrict__ spB, float* __restrict__ xi, float* __restrict__ fi,
    float* __restrict__ phi,
    const float* __restrict__ dist, const float* __restrict__ vec,
    const float* __restrict__ swv, float* __restrict__ dir, float* __restrict__ rb)
{
  const int b = blockIdx.x, tid = threadIdx.x;
  if (b < 33){
    int t = b/3, l = b%3;
    const float* src = wp.p[t] + (size_t)l*16384;
    __bf16* out = wt + (size_t)b*16384;
    for (int it=0; it<8; ++it){
      int fi_ = it*256 + tid;
      int kc = fi_>>9, ni = (fi_>>6)&7, lane = fi_&63;
      int n  = ni*16 + (lane&15);
      int k0 = kc*32 + (lane>>4)*8;
      bf16x8 v;
      #pragma unroll
      for (int j=0;j<8;++j) v[j] = (__bf16)src[(k0+j)*DIM + n];
      *(bf16x8*)(out + (size_t)fi_*8) = v;
    }
  } else if (b < 33 + 5000){
    int idx = (b-33)*256 + tid;     // < N*128
    int n = idx >> 7, d = idx & 127;
    xi[idx] = spW[species[n]*DIM + d] + spB[d];
    phi[idx] = 0.f;
    fi[idx] = 0.f;                  // plane 0
    fi[NFE + idx] = 0.f;            // plane 1
    fi[2L*NFE + idx] = 0.f;         // plane 2
  } else {
    int e = (b-5033)*256 + tid;
    if (e < N_EDGES){
      float d = dist[e];
      float s = swv[e];
      float inv = s / d;
      dir[e*3+0] = vec[e*3+0]*inv;
      dir[e*3+1] = vec[e*3+1]*inv;
      dir[e*3+2] = vec[e*3+2]*inv;
      const float eta = (16.0f/5.0f)*(16.0f/5.0f);
      #pragma unroll
      for (int j=0;j<NBASIS;j++){
        float c = (float)j * (5.0f/15.0f);
        float t2 = d - c;
        rb[e*NBASIS + j] = __expf(-eta*t2*t2);
      }
    }
  }
}

// mij = ai[src]*ai[dst]*(rb@radW + radB)*sw  AND  xi += segsum(mij).
// 64 edges/block, wave wv owns edges [16wv,16wv+16). radW cols in regs.
// r24: all 32 gather loads hoisted ahead of the accumulate loop (2 groups
// of 8 edges) so L2 latency overlaps; (256,4) bound guards occupancy.
__global__ __launch_bounds__(256,4) void mij_segsum(
    const __bf16* __restrict__ ai, const int* __restrict__ esrc, const int* __restrict__ edst,
    const float* __restrict__ swv, const float* __restrict__ rb,
    const float* __restrict__ radW, const float* __restrict__ radB,
    __bf16* __restrict__ mij, float* __restrict__ xi)
{
  __shared__ float sRb[64*NBASIS];
  __shared__ int   sS[64], sD[64];
  __shared__ float sSw[64];
  int tid = threadIdx.x;
  int e0 = blockIdx.x * 64;
  *(float4*)(sRb + tid*4) = *(const float4*)(rb + (long)e0*NBASIS + tid*4);
  if (tid < 64){
    sS[tid]  = esrc[e0+tid];
    sD[tid]  = edst[e0+tid];
    sSw[tid] = swv[e0+tid];
  }
  const int wv = tid>>6, lane = tid&63;
  const int d = lane*2;
  float2 rw[NBASIS];
  #pragma unroll
  for (int j=0;j<NBASIS;j++)
    rw[j] = *(const float2*)(radW + j*DIM + d);
  float2 rB = *(const float2*)(radB + d);
  __syncthreads();

  // hoisted gathers: issue all 32 row loads up front (independent)
  bf16x2 pas[16], pad[16];
  #pragma unroll
  for (int i=0;i<16;i++){
    int el = wv*16 + i;
    pas[i] = *(const bf16x2*)(ai + (long)sS[el]*DIM + d);
    pad[i] = *(const bf16x2*)(ai + (long)sD[el]*DIM + d);
  }

  float sx=0.f, sy=0.f;
  int cur = sS[wv*16];
  #pragma unroll
  for (int i=0;i<16;i++){
    int el = wv*16 + i;
    int n = sS[el];
    if (n != cur){                       // wave-uniform branch
      atomicAdd(&xi[(long)cur*DIM+d  ], sx);
      atomicAdd(&xi[(long)cur*DIM+d+1], sy);
      sx=0.f; sy=0.f; cur=n;
    }
    float acc0 = 0.f, acc1 = 0.f;
    #pragma unroll
    for (int j=0;j<NBASIS;j++){
      float rbv = sRb[el*NBASIS+j];
      acc0 += rbv*rw[j].x;
      acc1 += rbv*rw[j].y;
    }
    float sw_ = sSw[el];
    float m0 = (float)pas[i][0]*(float)pad[i][0]*(acc0+rB.x)*sw_;
    float m1 = (float)pas[i][1]*(float)pad[i][1]*(acc1+rB.y)*sw_;
    bf16x2 m; m[0]=(__bf16)m0; m[1]=(__bf16)m1;
    *(bf16x2*)(mij + (long)(e0+el)*DIM + d) = m;
    sx += m0; sy += m1;
  }
  atomicAdd(&xi[(long)cur*DIM+d  ], sx);
  atomicAdd(&xi[(long)cur*DIM+d+1], sy);
}

extern "C" void kernel_launch(void* const* d_in, const int* in_sizes, int n_in,
                              void* d_out, int out_size, void* d_ws, size_t ws_size,
                              hipStream_t stream) {
  const int*   species = (const int*)  d_in[0];
  const int*   esrc    = (const int*)  d_in[1];
  const int*   edst    = (const int*)  d_in[2];
  const float* dist    = (const float*)d_in[3];
  const float* vec     = (const float*)d_in[4];
  const float* swv     = (const float*)d_in[5];
  const float* spW     = (const float*)d_in[6];
  const float* spB     = (const float*)d_in[7];
  const float* radW    = (const float*)d_in[8];
  const float* radB    = (const float*)d_in[9];
  const float* aW1=(const float*)d_in[10], *aB1=(const float*)d_in[11], *aW2=(const float*)d_in[12], *aB2=(const float*)d_in[13];
  const float* FW1=(const float*)d_in[14], *FB1=(const float*)d_in[15], *FW2=(const float*)d_in[16], *FB2=(const float*)d_in[17];
  const float* fW1=(const float*)d_in[18], *fB1=(const float*)d_in[19], *fW2=(const float*)d_in[20], *fB2=(const float*)d_in[21];
  const float* RW1=(const float*)d_in[22], *RB1=(const float*)d_in[23], *RW2=(const float*)d_in[24], *RB2=(const float*)d_in[25];
  const float* rW1=(const float*)d_in[26], *rB1=(const float*)d_in[27], *rW2=(const float*)d_in[28], *rB2=(const float*)d_in[29];
  const float* uW1=(const float*)d_in[30], *uB1=(const float*)d_in[31], *uW2=(const float*)d_in[32], *uB2=(const float*)d_in[33];

  const long NF = (long)N_NODES*DIM;      // 1,280,000
  const long EF = (long)N_EDGES*DIM;      // 20,480,000
  float* ws   = (float*)d_ws;
  float* xi   = ws;
  float* Rv   = xi   + NF;
  float* uv   = Rv   + NF;
  float* phi  = uv   + NF;
  float* fi   = phi  + NF;                // 3 planes of NF
  float* di   = fi   + 3*NF;              // 3 planes of NF
  float* dir  = di   + 3*NF;
  float* rb   = dir  + 3L*N_EDGES;
  char* bp = (char*)(rb + 16L*N_EDGES);
  size_t off = ((size_t)(bp - (char*)d_ws) + 15) & ~(size_t)15;
  __bf16* ai   = (__bf16*)((char*)d_ws + off);
  __bf16* mij  = ai  + NF;
  __bf16* wt   = mij + EF;                // 33 x 128x128 bf16 (swizzled)

  // swizzled bf16 weights: tensor order a1,a2,F1,f1,f2,R1,R2,r1,r2,u1,u2
  WPtrs wp;
  wp.p[0]=aW1; wp.p[1]=aW2; wp.p[2]=FW1; wp.p[3]=fW1; wp.p[4]=fW2;
  wp.p[5]=RW1; wp.p[6]=RW2; wp.p[7]=rW1; wp.p[8]=rW2; wp.p[9]=uW1; wp.p[10]=uW2;

  // one-shot setup: 33 convert + 5000 init + 625 geom = 5658 blocks
  setup_all<<<5658, 256, 0, stream>>>(wp, wt,
                                      species, spW, spB, xi, fi, phi,
                                      dist, vec, swv, dir, rb);

  const int nodeB = (N_NODES + 63)/64;        // 157 (node part of mlp_layer)
  const int edgeB = N_EDGES/128;              // 1250
  #define WT(t,l) (wt + (size_t)((t)*3+(l))*16384)

  // a-MLP for layer 0 (layers 1,2 produced by node_upd_a)
  mlp_a<<<N_NODES/16, 64, 0, stream>>>(xi, WT(0,0), aB1, WT(1,0), aB2, ai);

  for (int l=0;l<3;l++){
    const long bo = (long)l*DIM;

    // mij (bf16) + xi += segsum(mij)   [fused, atomics]
    mij_segsum<<<N_EDGES/64, 256, 0, stream>>>(ai, esrc, edst, swv, rb,
                                               radW + (long)l*NBASIS*DIM, radB + bo,
                                               mij, xi);
    // combined: [node] Rv,uv  +  [edge] f/F[/r] MLPs with wave-local
    // fi/phi segment reductions (no ef/ephi in HBM; plane-coalesced atomics)
    if (l == 0)
      mlp_layer<false><<<nodeB+edgeB, 256, 0, stream>>>(
          nodeB, mij, esrc, dir,
          WT(3,l), fB1+bo, WT(4,l), fB2+bo,
          WT(2,l), FB1+bo, FW2+(long)l*DIM, FB2+l,
          nullptr, nullptr, nullptr, nullptr, nullptr,
          fi, phi,
          xi, WT(5,l), RB1+bo, WT(6,l), RB2+bo,
          WT(9,l), uB1+bo, WT(10,l), uB2+bo, Rv, uv);
    else
      mlp_layer<true><<<nodeB+edgeB, 256, 0, stream>>>(
          nodeB, mij, esrc, dir,
          WT(3,l), fB1+bo, WT(4,l), fB2+bo,
          WT(2,l), FB1+bo, FW2+(long)l*DIM, FB2+l,
          WT(7,l), rB1+bo, WT(8,l), rB2+bo, swv,
          fi, phi,
          xi, WT(5,l), RB1+bo, WT(6,l), RB2+bo,
          WT(9,l), uB1+bo, WT(10,l), uB2+bo, Rv, uv);
    // fused: di/scal/xi update + a-MLP(l+1); zeroes phi; out on l==2
    int ln = (l < 2) ? (l+1) : 0;
    node_upd_a<<<N_NODES/16, 64, 0, stream>>>(
        Rv, uv, fi, di, xi, phi, (float*)d_out,
        WT(0,ln), aB1+(long)ln*DIM, WT(1,ln), aB2+(long)ln*DIM, ai, l);
  }
}